// Round 14
// baseline (136.339 us; speedup 1.0000x reference)
//
#include <hip/hip_runtime.h>

#define NPTS  4096
#define KNN   16
#define K1    17            // KNN + self
#define NBLK  64            // candidate blocks per batch == wave width
#define CELLS 4096          // 16^3 Morton cells
#define EPSF  1e-10f

__device__ __forceinline__ unsigned umin_(unsigned a, unsigned b) { return a < b ? a : b; }
__device__ __forceinline__ unsigned umax_(unsigned a, unsigned b) { return a < b ? b : a; }
__device__ __forceinline__ unsigned rdlane(unsigned v, int l) {
    return (unsigned)__builtin_amdgcn_readlane((int)v, l);
}

// cheap cross-lane primitives (DPP = VALU, ds_swizzle = DS pipe, shfl = ds_permute)
#define DPP_XOR1(v)  ((unsigned)__builtin_amdgcn_update_dpp(0, (int)(v), 0xB1, 0xF, 0xF, true))
#define DPP_XOR2(v)  ((unsigned)__builtin_amdgcn_update_dpp(0, (int)(v), 0x4E, 0xF, 0xF, true))
#define SWZ_XOR(v,J) ((unsigned)__builtin_amdgcn_ds_swizzle((int)(v), ((J) << 10) | 0x1F))
#define DPP_SHR1(v)  ((unsigned)__builtin_amdgcn_update_dpp(0, (int)(v), 0x111, 0xF, 0xF, true))
#define DPPF_SHR(vf, CTRL) __uint_as_float((unsigned)__builtin_amdgcn_update_dpp(0, (int)__float_as_uint(vf), CTRL, 0xF, 0xF, true))
#define LXOR1(v)  DPP_XOR1(v)
#define LXOR2(v)  DPP_XOR2(v)
#define LXOR4(v)  SWZ_XOR(v, 4)
#define LXOR8(v)  SWZ_XOR(v, 8)
#define LXOR16(v) SWZ_XOR(v, 16)
#define LXOR32(v) ((unsigned)__shfl_xor((int)(v), 32))

// float min/max across lanes via uint primitives (all inputs finite)
#define FXMIN(a, XORF) do {                                                   \
    unsigned o_ = XORF(__float_as_uint(a));                                   \
    a = fminf(a, __uint_as_float(o_));                                        \
} while (0)
#define FXMAX(a, XORF) do {                                                   \
    unsigned o_ = XORF(__float_as_uint(a));                                   \
    a = fmaxf(a, __uint_as_float(o_));                                        \
} while (0)

// one compare-exchange stage applied to BOTH sort chains (ILP)
#define BSTEP(K, XORF) do {                                                   \
    unsigned o1_ = XORF(arr), o2_ = XORF(bk);                                 \
    bool tm_ = (((lane & (J_)) == 0) == ((lane & (K)) == 0));                 \
    unsigned mn1_ = umin_(arr, o1_), mx1_ = umax_(arr, o1_);                  \
    unsigned mn2_ = umin_(bk, o2_),  mx2_ = umax_(bk, o2_);                   \
    arr = tm_ ? mn1_ : mx1_; bk = tm_ ? mn2_ : mx2_;                          \
} while (0)

// spread 4 bits to positions 0,3,6,9
__device__ __forceinline__ unsigned sp4(int v) {
    unsigned x = (unsigned)v;
    return (x & 1u) | ((x & 2u) << 2) | ((x & 4u) << 4) | ((x & 8u) << 6);
}

// ---- Kernel 1: per-batch counting sort by 12-bit Morton cell + per-64-block
// bboxes. Sort is permutation-only (exactness never depends on it); bboxes
// are true min/max of actual points.
__global__ __launch_bounds__(1024) void sort_kernel(
    const float* __restrict__ pref,
    float4* __restrict__ wxyzw, int* __restrict__ widx, float4* __restrict__ wbb)
{
    __shared__ unsigned hist[CELLS];          // 16 KB
    __shared__ unsigned short cells[NPTS];    // 8 KB
    __shared__ unsigned wofs[16];
    const int tid  = threadIdx.x;
    const int lane = tid & 63, w = tid >> 6;
    const int b = blockIdx.x;
    const float* prb = pref + (size_t)b * NPTS * 3;
    const size_t base = (size_t)b * NPTS;

    for (int t = tid; t < CELLS; t += 1024) hist[t] = 0u;
    __syncthreads();

    for (int p = tid; p < NPTS; p += 1024) {
        float x = prb[3 * p + 0], y = prb[3 * p + 1], z = prb[3 * p + 2];
        int cx = min(15, max(0, (int)((x + 4.0f) * 2.0f)));
        int cy = min(15, max(0, (int)((y + 4.0f) * 2.0f)));
        int cz = min(15, max(0, (int)((z + 4.0f) * 2.0f)));
        unsigned m = sp4(cx) | (sp4(cy) << 1) | (sp4(cz) << 2);
        cells[p] = (unsigned short)m;
        atomicAdd(&hist[m], 1u);
    }
    __syncthreads();

    // Exclusive scan of hist[4096]; thread t owns cells 4t..4t+3.
    unsigned l0 = hist[4 * tid + 0], l1 = hist[4 * tid + 1];
    unsigned l2 = hist[4 * tid + 2], l3 = hist[4 * tid + 3];
    unsigned s = l0 + l1 + l2 + l3;
    unsigned run = s;
#pragma unroll
    for (int d = 1; d < 64; d <<= 1) {
        unsigned o = __shfl_up(run, d);
        if (lane >= d) run += o;
    }
    if (lane == 63) wofs[w] = run;
    __syncthreads();
    if (tid == 0) {
        unsigned acc = 0;
#pragma unroll
        for (int k = 0; k < 16; ++k) { unsigned t2 = wofs[k]; wofs[k] = acc; acc += t2; }
    }
    __syncthreads();
    unsigned excl = wofs[w] + run - s;
    hist[4 * tid + 0] = excl;
    hist[4 * tid + 1] = excl + l0;
    hist[4 * tid + 2] = excl + l0 + l1;
    hist[4 * tid + 3] = excl + l0 + l1 + l2;
    __syncthreads();

    for (int p = tid; p < NPTS; p += 1024) {
        unsigned c = cells[p];
        unsigned pos = atomicAdd(&hist[c], 1u);
        wxyzw[base + pos] = make_float4(prb[3 * p + 0], prb[3 * p + 1], prb[3 * p + 2], 0.f);
        widx[base + pos]  = p;
    }
    __syncthreads();

    // Per-block bboxes: wave w handles blocks w, w+16, w+32, w+48.
    // DPP/swizzle min/max ladder (cheaper than shfl_xor = ds_permute).
#pragma unroll
    for (int rep = 0; rep < 4; ++rep) {
        int blk = w + rep * 16;
        float4 c = wxyzw[base + blk * 64 + lane];
        float mnx = c.x, mxx = c.x, mny = c.y, mxy2 = c.y, mnz = c.z, mxz = c.z;
        FXMIN(mnx, LXOR1);  FXMAX(mxx, LXOR1);  FXMIN(mny, LXOR1);
        FXMAX(mxy2, LXOR1); FXMIN(mnz, LXOR1);  FXMAX(mxz, LXOR1);
        FXMIN(mnx, LXOR2);  FXMAX(mxx, LXOR2);  FXMIN(mny, LXOR2);
        FXMAX(mxy2, LXOR2); FXMIN(mnz, LXOR2);  FXMAX(mxz, LXOR2);
        FXMIN(mnx, LXOR4);  FXMAX(mxx, LXOR4);  FXMIN(mny, LXOR4);
        FXMAX(mxy2, LXOR4); FXMIN(mnz, LXOR4);  FXMAX(mxz, LXOR4);
        FXMIN(mnx, LXOR8);  FXMAX(mxx, LXOR8);  FXMIN(mny, LXOR8);
        FXMAX(mxy2, LXOR8); FXMIN(mnz, LXOR8);  FXMAX(mxz, LXOR8);
        FXMIN(mnx, LXOR16); FXMAX(mxx, LXOR16); FXMIN(mny, LXOR16);
        FXMAX(mxy2, LXOR16); FXMIN(mnz, LXOR16); FXMAX(mxz, LXOR16);
        FXMIN(mnx, LXOR32); FXMAX(mxx, LXOR32); FXMIN(mny, LXOR32);
        FXMAX(mxy2, LXOR32); FXMIN(mnz, LXOR32); FXMAX(mxz, LXOR32);
        if (lane == 0) {
            wbb[((size_t)b * NBLK + blk) * 2 + 0] = make_float4(mnx, mny, mnz, 0.f);
            wbb[((size_t)b * NBLK + blk) * 2 + 1] = make_float4(mxx, mxy2, mxz, 0.f);
        }
    }
}

// DPP-based insertion of broadcast key kk_ into lane-sliced sorted arr
#define EVENTS(KEY) do {                                                      \
    unsigned long long m_ = __ballot((KEY) < thr);                            \
    if (m_) {                                                                 \
        do {                                                                  \
            int l_ = __ffsll(m_) - 1;                                         \
            m_ &= m_ - 1;                                                     \
            unsigned kk_ = rdlane(KEY, l_);                                   \
            unsigned long long lt_ = __ballot(arr < kk_) & 0x1FFFFull;        \
            int pos_ = __popcll(lt_);                                         \
            unsigned up_ = DPP_SHR1(arr);                                     \
            unsigned a15_ = rdlane(arr, 15);                                  \
            up_ = (lane == 16) ? a15_ : up_;                                  \
            arr = (lane == pos_) ? kk_ : ((lane > pos_) ? up_ : arr);         \
        } while (m_);                                                         \
        thr = rdlane(arr, K1 - 1);                                            \
    } } while (0)

// ---- Kernel 2: one query per wave (R10 structure, proven best); hash-
// permuted query ids; distance-ordered bbox walk with early exit; exact
// top-17; fused block-level reduction via one atomicAdd per block.
__global__ __launch_bounds__(256, 8) void knn_main_kernel(
    const float* __restrict__ ppred,
    const float4* __restrict__ wxyzw, const int* __restrict__ widx,
    const float4* __restrict__ wbb, float* __restrict__ out, float scale, int NQ)
{
    __shared__ float wsum[4];
    const int lane = threadIdx.x & 63;
    const int wv   = blockIdx.x * 4 + (threadIdx.x >> 6);
    // odd multiplier mod pow2 is a bijection; mixes spatial regions across waves
    const int q = ((NQ & (NQ - 1)) == 0) ? (int)(((unsigned)wv * 26765u) & (unsigned)(NQ - 1)) : wv;

    const int b = q >> 12;
    const int p = q & (NPTS - 1);              // sorted position = query
    const size_t base = (size_t)b * NPTS;
    const int p0 = p & ~63, ownblk = p >> 6;

    const float4 qc = wxyzw[base + p];         // uniform -> broadcast
    const float qx = qc.x, qy = qc.y, qz = qc.z;

    // own-block candidate keys (self d2 == +0.0 -> key = p = minimum)
    unsigned arr;
    {
        float4 c = wxyzw[base + p0 + lane];
        float dx = c.x - qx, dy = c.y - qy, dz = c.z - qz;
        float d2 = dx * dx + dy * dy + dz * dz;
        arr = (__float_as_uint(d2) & 0xFFFFF000u) | (unsigned)(p0 + lane);
    }
    // bbox lower-bound keys: same truncation as real keys; blk in the index
    // field (blk <= any j in block) => bkey <= every real key in the block.
    unsigned bk;
    {
        float4 mn4 = wbb[((size_t)b * NBLK + lane) * 2 + 0];
        float4 mx4 = wbb[((size_t)b * NBLK + lane) * 2 + 1];
        float ddx = fmaxf(fmaxf(mn4.x - qx, qx - mx4.x), 0.0f);
        float ddy = fmaxf(fmaxf(mn4.y - qy, qy - mx4.y), 0.0f);
        float ddz = fmaxf(fmaxf(mn4.z - qz, qz - mx4.z), 0.0f);
        float bd2 = ddx * ddx + ddy * ddy + ddz * ddz;
        bk = (__float_as_uint(bd2) & 0xFFFFF000u) | (unsigned)lane;
        bk = (lane == ownblk) ? 0xFFFFFFFFu : bk;   // sentinel: never walked
    }

    // joint bitonic sort of arr and bk (ascending), ILP'd through one network
    {
        int J_;
        J_ = 1;  BSTEP(2,  LXOR1);
        J_ = 2;  BSTEP(4,  LXOR2);  J_ = 1; BSTEP(4,  LXOR1);
        J_ = 4;  BSTEP(8,  LXOR4);  J_ = 2; BSTEP(8,  LXOR2);  J_ = 1; BSTEP(8,  LXOR1);
        J_ = 8;  BSTEP(16, LXOR8);  J_ = 4; BSTEP(16, LXOR4);  J_ = 2; BSTEP(16, LXOR2);  J_ = 1; BSTEP(16, LXOR1);
        J_ = 16; BSTEP(32, LXOR16); J_ = 8; BSTEP(32, LXOR8);  J_ = 4; BSTEP(32, LXOR4);  J_ = 2; BSTEP(32, LXOR2); J_ = 1; BSTEP(32, LXOR1);
        J_ = 32; BSTEP(64, LXOR32); J_ = 16; BSTEP(64, LXOR16); J_ = 8; BSTEP(64, LXOR8); J_ = 4; BSTEP(64, LXOR4); J_ = 2; BSTEP(64, LXOR2); J_ = 1; BSTEP(64, LXOR1);
    }
    unsigned thr = rdlane(arr, K1 - 1);

    // ordered walk: blocks by ascending lower bound; break = prune rest (exact:
    // truncation is monotone, bkey <= real keys, thr only decreases).
    int k = 0;
    unsigned bcur = rdlane(bk, 0);
    bool have = (bcur < thr);
    float4 cur;
    if (have) cur = wxyzw[base + (int)(bcur & 0xFFFu) * 64 + lane];
    while (have) {
        unsigned bnext = rdlane(bk, k + 1);
        bool pf = (bnext < thr);               // prefetch decision (conservative)
        float4 nxt;
        if (pf) nxt = wxyzw[base + (int)(bnext & 0xFFFu) * 64 + lane];
        int jbase = (int)(bcur & 0xFFFu) * 64;
        float dx = cur.x - qx, dy = cur.y - qy, dz = cur.z - qz;
        float d2 = dx * dx + dy * dy + dz * dz;
        unsigned key = (__float_as_uint(d2) & 0xFFFFF000u) | (unsigned)(jbase + lane);
        EVENTS(key);                           // tightens thr
        ++k;
        bcur = bnext;
        have = (bcur < thr);                   // thr only decreased: pf false => have false
        cur = nxt;
    }

    // Epilogue: lanes 1..16 hold the 16 nearest neighbors (lane 0 = self).
    const float* ppb = ppred + (size_t)b * NPTS * 3;
    const int iorig = widx[base + p];
    float s = 0.f;
    if (lane >= 1 && lane <= KNN) {
        int js = (int)(arr & 0xFFFu);
        float4 rc = wxyzw[base + js];
        float rx = rc.x - qx, ry = rc.y - qy, rz = rc.z - qz;
        float dref = sqrtf(rx * rx + ry * ry + rz * rz);
        int nj = widx[base + js];
        float px = ppb[3 * iorig + 0], py = ppb[3 * iorig + 1], pz = ppb[3 * iorig + 2];
        float ax = ppb[3 * nj + 0] - px;
        float ay = ppb[3 * nj + 1] - py;
        float az = ppb[3 * nj + 2] - pz;
        float dpred = sqrtf(ax * ax + ay * ay + az * az);
        s = fmaxf(dpred / (dref + EPSF) - 1.0f, 0.0f);
    }
    // DPP prefix-add within rows of 16; lanes 0..16 hold all nonzeros.
    s += DPPF_SHR(s, 0x111);
    s += DPPF_SHR(s, 0x112);
    s += DPPF_SHR(s, 0x114);
    s += DPPF_SHR(s, 0x118);
    float t15 = __uint_as_float(rdlane(__float_as_uint(s), 15));
    float t16 = __uint_as_float(rdlane(__float_as_uint(s), 16));

    // fused block reduction: one atomicAdd per 4-wave block
    if (lane == 0) wsum[threadIdx.x >> 6] = t15 + t16;
    __syncthreads();
    if (threadIdx.x == 0)
        atomicAdd(out, ((wsum[0] + wsum[1]) + (wsum[2] + wsum[3])) * scale);
}

extern "C" void kernel_launch(void* const* d_in, const int* in_sizes, int n_in,
                              void* d_out, int out_size, void* d_ws, size_t ws_size,
                              hipStream_t stream) {
    const float* pref  = (const float*)d_in[0];
    const float* ppred = (const float*)d_in[1];
    float* out = (float*)d_out;

    const int B  = in_sizes[0] / (NPTS * 3);
    const int NQ = B * NPTS;
    const float scale = 1.0f / ((float)NQ * (float)KNN);

    char* ws = (char*)d_ws;
    float4* wxyzw = (float4*)ws;                                   // B*N*16
    int*    widx  = (int*)   (ws + (size_t)B * NPTS * 16);         // B*N*4
    float4* wbb   = (float4*)(ws + (size_t)B * NPTS * 20);         // B*64*2*16

    hipMemsetAsync(d_out, 0, sizeof(float), stream);
    sort_kernel<<<dim3(B), dim3(1024), 0, stream>>>(pref, wxyzw, widx, wbb);
    knn_main_kernel<<<dim3(NQ / 4), dim3(256), 0, stream>>>(ppred, wxyzw, widx, wbb, out, scale, NQ);
}

// Round 15
// 132.679 us; speedup vs baseline: 1.0276x; 1.0276x over previous
//
#include <hip/hip_runtime.h>

#define NPTS  4096
#define KNN   16
#define K1    17            // KNN + self
#define NBLK  64            // candidate blocks per batch == wave width
#define CELLS 4096          // 16^3 Morton cells
#define EPSF  1e-10f

__device__ __forceinline__ unsigned umin_(unsigned a, unsigned b) { return a < b ? a : b; }
__device__ __forceinline__ unsigned umax_(unsigned a, unsigned b) { return a < b ? b : a; }
__device__ __forceinline__ unsigned rdlane(unsigned v, int l) {
    return (unsigned)__builtin_amdgcn_readlane((int)v, l);
}

// cheap cross-lane primitives (DPP = VALU, ds_swizzle = DS pipe, shfl = ds_permute)
#define DPP_XOR1(v)  ((unsigned)__builtin_amdgcn_update_dpp(0, (int)(v), 0xB1, 0xF, 0xF, true))
#define DPP_XOR2(v)  ((unsigned)__builtin_amdgcn_update_dpp(0, (int)(v), 0x4E, 0xF, 0xF, true))
#define SWZ_XOR(v,J) ((unsigned)__builtin_amdgcn_ds_swizzle((int)(v), ((J) << 10) | 0x1F))
#define DPP_SHR1(v)  ((unsigned)__builtin_amdgcn_update_dpp(0, (int)(v), 0x111, 0xF, 0xF, true))
#define DPPF_SHR(vf, CTRL) __uint_as_float((unsigned)__builtin_amdgcn_update_dpp(0, (int)__float_as_uint(vf), CTRL, 0xF, 0xF, true))
#define LXOR1(v)  DPP_XOR1(v)
#define LXOR2(v)  DPP_XOR2(v)
#define LXOR4(v)  SWZ_XOR(v, 4)
#define LXOR8(v)  SWZ_XOR(v, 8)
#define LXOR16(v) SWZ_XOR(v, 16)
#define LXOR32(v) ((unsigned)__shfl_xor((int)(v), 32))

// one compare-exchange stage applied to FIVE chains (4 query arrays + bk)
#define BSTEP5(K, XORF) do {                                                  \
    unsigned o0_ = XORF(arr0), o1_ = XORF(arr1);                              \
    unsigned o2_ = XORF(arr2), o3_ = XORF(arr3), ob_ = XORF(bk);              \
    bool tm_ = (((lane & (J_)) == 0) == ((lane & (K)) == 0));                 \
    arr0 = tm_ ? umin_(arr0, o0_) : umax_(arr0, o0_);                         \
    arr1 = tm_ ? umin_(arr1, o1_) : umax_(arr1, o1_);                         \
    arr2 = tm_ ? umin_(arr2, o2_) : umax_(arr2, o2_);                         \
    arr3 = tm_ ? umin_(arr3, o3_) : umax_(arr3, o3_);                         \
    bk   = tm_ ? umin_(bk,   ob_) : umax_(bk,   ob_);                         \
} while (0)

// spread 4 bits to positions 0,3,6,9
__device__ __forceinline__ unsigned sp4(int v) {
    unsigned x = (unsigned)v;
    return (x & 1u) | ((x & 2u) << 2) | ((x & 4u) << 4) | ((x & 8u) << 6);
}

// ---- Kernel 1: per-batch counting sort by 12-bit Morton cell + per-64-block
// bboxes (proven R10 version). Sort is permutation-only; bboxes true min/max.
__global__ __launch_bounds__(1024) void sort_kernel(
    const float* __restrict__ pref,
    float4* __restrict__ wxyzw, int* __restrict__ widx, float4* __restrict__ wbb)
{
    __shared__ unsigned hist[CELLS];          // 16 KB
    __shared__ unsigned short cells[NPTS];    // 8 KB
    __shared__ unsigned wofs[16];
    const int tid  = threadIdx.x;
    const int lane = tid & 63, w = tid >> 6;
    const int b = blockIdx.x;
    const float* prb = pref + (size_t)b * NPTS * 3;
    const size_t base = (size_t)b * NPTS;

    for (int t = tid; t < CELLS; t += 1024) hist[t] = 0u;
    __syncthreads();

    for (int p = tid; p < NPTS; p += 1024) {
        float x = prb[3 * p + 0], y = prb[3 * p + 1], z = prb[3 * p + 2];
        int cx = min(15, max(0, (int)((x + 4.0f) * 2.0f)));
        int cy = min(15, max(0, (int)((y + 4.0f) * 2.0f)));
        int cz = min(15, max(0, (int)((z + 4.0f) * 2.0f)));
        unsigned m = sp4(cx) | (sp4(cy) << 1) | (sp4(cz) << 2);
        cells[p] = (unsigned short)m;
        atomicAdd(&hist[m], 1u);
    }
    __syncthreads();

    unsigned l0 = hist[4 * tid + 0], l1 = hist[4 * tid + 1];
    unsigned l2 = hist[4 * tid + 2], l3 = hist[4 * tid + 3];
    unsigned s = l0 + l1 + l2 + l3;
    unsigned run = s;
#pragma unroll
    for (int d = 1; d < 64; d <<= 1) {
        unsigned o = __shfl_up(run, d);
        if (lane >= d) run += o;
    }
    if (lane == 63) wofs[w] = run;
    __syncthreads();
    if (tid == 0) {
        unsigned acc = 0;
#pragma unroll
        for (int k = 0; k < 16; ++k) { unsigned t2 = wofs[k]; wofs[k] = acc; acc += t2; }
    }
    __syncthreads();
    unsigned excl = wofs[w] + run - s;
    hist[4 * tid + 0] = excl;
    hist[4 * tid + 1] = excl + l0;
    hist[4 * tid + 2] = excl + l0 + l1;
    hist[4 * tid + 3] = excl + l0 + l1 + l2;
    __syncthreads();

    for (int p = tid; p < NPTS; p += 1024) {
        unsigned c = cells[p];
        unsigned pos = atomicAdd(&hist[c], 1u);
        wxyzw[base + pos] = make_float4(prb[3 * p + 0], prb[3 * p + 1], prb[3 * p + 2], 0.f);
        widx[base + pos]  = p;
    }
    __syncthreads();

#pragma unroll
    for (int rep = 0; rep < 4; ++rep) {
        int blk = w + rep * 16;
        float4 c = wxyzw[base + blk * 64 + lane];
        float mnx = c.x, mxx = c.x, mny = c.y, mxy2 = c.y, mnz = c.z, mxz = c.z;
#pragma unroll
        for (int d = 32; d > 0; d >>= 1) {
            mnx  = fminf(mnx,  __shfl_xor(mnx,  d));
            mxx  = fmaxf(mxx,  __shfl_xor(mxx,  d));
            mny  = fminf(mny,  __shfl_xor(mny,  d));
            mxy2 = fmaxf(mxy2, __shfl_xor(mxy2, d));
            mnz  = fminf(mnz,  __shfl_xor(mnz,  d));
            mxz  = fmaxf(mxz,  __shfl_xor(mxz,  d));
        }
        if (lane == 0) {
            wbb[((size_t)b * NBLK + blk) * 2 + 0] = make_float4(mnx, mny, mnz, 0.f);
            wbb[((size_t)b * NBLK + blk) * 2 + 1] = make_float4(mxx, mxy2, mxz, 0.f);
        }
    }
}

// DPP-based insertion of broadcast keys into a lane-sliced sorted array.
// Self-correcting: key >= current arr[16] lands at pos >= 17 (garbage lanes).
#define EVQ(KEY, ARR, THR) do {                                               \
    unsigned long long m_ = __ballot((KEY) < THR);                            \
    if (m_) {                                                                 \
        do {                                                                  \
            int l_ = __ffsll(m_) - 1;                                         \
            m_ &= m_ - 1;                                                     \
            unsigned kk_ = rdlane(KEY, l_);                                   \
            unsigned long long lt_ = __ballot(ARR < kk_) & 0x1FFFFull;        \
            int pos_ = __popcll(lt_);                                         \
            unsigned up_ = DPP_SHR1(ARR);                                     \
            unsigned a15_ = rdlane(ARR, 15);                                  \
            up_ = (lane == 16) ? a15_ : up_;                                  \
            ARR = (lane == pos_) ? kk_ : ((lane > pos_) ? up_ : ARR);         \
        } while (m_);                                                         \
        THR = rdlane(ARR, K1 - 1);                                            \
    } } while (0)

// up-rounded threshold radius (trunc key -> upper bound on true d2)
#define THRUP(T) sqrtf(__uint_as_float(((T) & 0xFFFFF000u) + 0x1000u))
#define LIMIT()  (fmaxf(fmaxf(THRUP(thr0), THRUP(thr1)),                      \
                        fmaxf(THRUP(thr2), THRUP(thr3))) + D0)

// per-query stretch epilogue; lanes 1..16 of ARR hold the 16 nearest
#define EPI(ARR, P, QX, QY, QZ) do {                                          \
    const int iorig_ = widx[base + (P)];                                      \
    float s_ = 0.f;                                                           \
    if (lane >= 1 && lane <= KNN) {                                           \
        int js_ = (int)((ARR) & 0xFFFu);                                      \
        float4 rc_ = wxyzw[base + js_];                                       \
        float rx_ = rc_.x - (QX), ry_ = rc_.y - (QY), rz_ = rc_.z - (QZ);     \
        float dref_ = sqrtf(rx_ * rx_ + ry_ * ry_ + rz_ * rz_);               \
        int nj_ = widx[base + js_];                                           \
        float px_ = ppb[3 * iorig_ + 0], py_ = ppb[3 * iorig_ + 1], pz_ = ppb[3 * iorig_ + 2]; \
        float ax_ = ppb[3 * nj_ + 0] - px_;                                   \
        float ay_ = ppb[3 * nj_ + 1] - py_;                                   \
        float az_ = ppb[3 * nj_ + 2] - pz_;                                   \
        float dpred_ = sqrtf(ax_ * ax_ + ay_ * ay_ + az_ * az_);              \
        s_ = fmaxf(dpred_ / (dref_ + EPSF) - 1.0f, 0.0f);                     \
    }                                                                         \
    s_ += DPPF_SHR(s_, 0x111);                                                \
    s_ += DPPF_SHR(s_, 0x112);                                                \
    s_ += DPPF_SHR(s_, 0x114);                                                \
    s_ += DPPF_SHR(s_, 0x118);                                                \
    acc += __uint_as_float(rdlane(__float_as_uint(s_), 15))                   \
         + __uint_as_float(rdlane(__float_as_uint(s_), 16));                  \
} while (0)

// ---- Kernel 2: FOUR consecutive-sorted-position queries per wave (same
// own-block); shared candidate loads + shared walk order (q0's bbox keys,
// with D0-margin exit: dist_i(B) >= dist_0(B) - D0, trunc rounds down, thr
// rounds up => every block possibly holding any query's top-16 is visited).
// 8192 waves total (vs 32768) to beat the wave-dispatch-rate cap.
__global__ __launch_bounds__(256, 8) void knn_main_kernel(
    const float* __restrict__ ppred,
    const float4* __restrict__ wxyzw, const int* __restrict__ widx,
    const float4* __restrict__ wbb, float* __restrict__ partials, int NG)
{
    const int lane = threadIdx.x & 63;
    const int wv   = blockIdx.x * 4 + (threadIdx.x >> 6);
    // odd multiplier mod pow2 is a bijection; mixes spatial regions
    const int g = ((NG & (NG - 1)) == 0) ? (int)(((unsigned)wv * 26765u) & (unsigned)(NG - 1)) : wv;

    const int q0id = g * 4;
    const int b  = q0id >> 12;
    const int p0 = q0id & (NPTS - 1);
    const int p1 = p0 + 1, p2 = p0 + 2, p3 = p0 + 3;
    const size_t base = (size_t)b * NPTS;
    const int pblk = p0 & ~63, ownblk = p0 >> 6;

    const float4 qc0 = wxyzw[base + p0];
    const float4 qc1 = wxyzw[base + p1];
    const float4 qc2 = wxyzw[base + p2];
    const float4 qc3 = wxyzw[base + p3];
    const float qx0 = qc0.x, qy0 = qc0.y, qz0 = qc0.z;
    const float qx1 = qc1.x, qy1 = qc1.y, qz1 = qc1.z;
    const float qx2 = qc2.x, qy2 = qc2.y, qz2 = qc2.z;
    const float qx3 = qc3.x, qy3 = qc3.y, qz3 = qc3.z;

    // D0 = max distance from q0 to the siblings (exact margin for the walk)
    float D0;
    {
        float ax = qx1 - qx0, ay = qy1 - qy0, az = qz1 - qz0;
        float bx = qx2 - qx0, by = qy2 - qy0, bz = qz2 - qz0;
        float cx = qx3 - qx0, cy = qy3 - qy0, cz = qz3 - qz0;
        float da = ax * ax + ay * ay + az * az;
        float db = bx * bx + by * by + bz * bz;
        float dc = cx * cx + cy * cy + cz * cz;
        D0 = sqrtf(fmaxf(fmaxf(da, db), dc));
    }

    // own-block keys for all 4 queries from ONE load (self d2 == +0.0 -> min)
    unsigned arr0, arr1, arr2, arr3;
    {
        float4 c = wxyzw[base + pblk + lane];
        unsigned jj = (unsigned)(pblk + lane);
        float dx, dy, dz, d2;
        dx = c.x - qx0; dy = c.y - qy0; dz = c.z - qz0;
        d2 = dx * dx + dy * dy + dz * dz;
        arr0 = (__float_as_uint(d2) & 0xFFFFF000u) | jj;
        dx = c.x - qx1; dy = c.y - qy1; dz = c.z - qz1;
        d2 = dx * dx + dy * dy + dz * dz;
        arr1 = (__float_as_uint(d2) & 0xFFFFF000u) | jj;
        dx = c.x - qx2; dy = c.y - qy2; dz = c.z - qz2;
        d2 = dx * dx + dy * dy + dz * dz;
        arr2 = (__float_as_uint(d2) & 0xFFFFF000u) | jj;
        dx = c.x - qx3; dy = c.y - qy3; dz = c.z - qz3;
        d2 = dx * dx + dy * dy + dz * dz;
        arr3 = (__float_as_uint(d2) & 0xFFFFF000u) | jj;
    }
    // q0's bbox lower-bound keys (walk order); sentinel at own block
    unsigned bk;
    {
        float4 mn4 = wbb[((size_t)b * NBLK + lane) * 2 + 0];
        float4 mx4 = wbb[((size_t)b * NBLK + lane) * 2 + 1];
        float ddx = fmaxf(fmaxf(mn4.x - qx0, qx0 - mx4.x), 0.0f);
        float ddy = fmaxf(fmaxf(mn4.y - qy0, qy0 - mx4.y), 0.0f);
        float ddz = fmaxf(fmaxf(mn4.z - qz0, qz0 - mx4.z), 0.0f);
        float bd2 = ddx * ddx + ddy * ddy + ddz * ddz;
        bk = (__float_as_uint(bd2) & 0xFFFFF000u) | (unsigned)lane;
        bk = (lane == ownblk) ? 0xFFFFFFFFu : bk;   // trunc -> NaN dist -> exits
    }

    // joint bitonic sort of 5 chains (ascending) through one network
    {
        int J_;
        J_ = 1;  BSTEP5(2,  LXOR1);
        J_ = 2;  BSTEP5(4,  LXOR2);  J_ = 1; BSTEP5(4,  LXOR1);
        J_ = 4;  BSTEP5(8,  LXOR4);  J_ = 2; BSTEP5(8,  LXOR2);  J_ = 1; BSTEP5(8,  LXOR1);
        J_ = 8;  BSTEP5(16, LXOR8);  J_ = 4; BSTEP5(16, LXOR4);  J_ = 2; BSTEP5(16, LXOR2);  J_ = 1; BSTEP5(16, LXOR1);
        J_ = 16; BSTEP5(32, LXOR16); J_ = 8; BSTEP5(32, LXOR8);  J_ = 4; BSTEP5(32, LXOR4);  J_ = 2; BSTEP5(32, LXOR2); J_ = 1; BSTEP5(32, LXOR1);
        J_ = 32; BSTEP5(64, LXOR32); J_ = 16; BSTEP5(64, LXOR16); J_ = 8; BSTEP5(64, LXOR8); J_ = 4; BSTEP5(64, LXOR4); J_ = 2; BSTEP5(64, LXOR2); J_ = 1; BSTEP5(64, LXOR1);
    }
    unsigned thr0 = rdlane(arr0, K1 - 1);
    unsigned thr1 = rdlane(arr1, K1 - 1);
    unsigned thr2 = rdlane(arr2, K1 - 1);
    unsigned thr3 = rdlane(arr3, K1 - 1);

    // shared ordered walk: ascending trunc(bd2_0); exit when even the
    // down-rounded q0 bound exceeds the up-rounded max radius + D0 (exact).
    float limit = LIMIT();
    int k = 0;
    unsigned bcur = rdlane(bk, 0);
    float bd = sqrtf(__uint_as_float(bcur & 0xFFFFF000u));
    bool have = (bd < limit);                  // NaN-safe
    float4 cur;
    if (have) cur = wxyzw[base + (int)(bcur & 0xFFFu) * 64 + lane];
    while (have) {
        unsigned bnext = rdlane(bk, k + 1);
        float bdn = sqrtf(__uint_as_float(bnext & 0xFFFFF000u));
        bool pf = (bdn < limit);               // stale limit: conservative (limit only shrinks)
        float4 nxt;
        if (pf) nxt = wxyzw[base + (int)(bnext & 0xFFFu) * 64 + lane];
        unsigned j = (unsigned)((int)(bcur & 0xFFFu) * 64 + lane);
        {
            float dx = cur.x - qx0, dy = cur.y - qy0, dz = cur.z - qz0;
            float d2 = dx * dx + dy * dy + dz * dz;
            unsigned key = (__float_as_uint(d2) & 0xFFFFF000u) | j;
            EVQ(key, arr0, thr0);
        }
        {
            float dx = cur.x - qx1, dy = cur.y - qy1, dz = cur.z - qz1;
            float d2 = dx * dx + dy * dy + dz * dz;
            unsigned key = (__float_as_uint(d2) & 0xFFFFF000u) | j;
            EVQ(key, arr1, thr1);
        }
        {
            float dx = cur.x - qx2, dy = cur.y - qy2, dz = cur.z - qz2;
            float d2 = dx * dx + dy * dy + dz * dz;
            unsigned key = (__float_as_uint(d2) & 0xFFFFF000u) | j;
            EVQ(key, arr2, thr2);
        }
        {
            float dx = cur.x - qx3, dy = cur.y - qy3, dz = cur.z - qz3;
            float d2 = dx * dx + dy * dy + dz * dz;
            unsigned key = (__float_as_uint(d2) & 0xFFFFF000u) | j;
            EVQ(key, arr3, thr3);
        }
        limit = LIMIT();
        ++k;
        bcur = bnext;
        have = pf && (bdn < limit);
        cur = nxt;
    }

    // 4 epilogues, accumulate one partial per wave
    const float* ppb = ppred + (size_t)b * NPTS * 3;
    float acc = 0.f;
    EPI(arr0, p0, qx0, qy0, qz0);
    EPI(arr1, p1, qx1, qy1, qz1);
    EPI(arr2, p2, qx2, qy2, qz2);
    EPI(arr3, p3, qx3, qy3, qz3);
    if (lane == 0) partials[wv] = acc;
}

// ---- Kernel 3: deterministic single-block final reduction.
__global__ __launch_bounds__(1024) void reduce_kernel(
    const float* __restrict__ partials, int n, float* __restrict__ out, float scale)
{
    __shared__ float wsum[16];
    float s = 0.f;
    for (int idx = threadIdx.x; idx < n; idx += 1024) s += partials[idx];
    for (int off = 32; off > 0; off >>= 1) s += __shfl_down(s, off);
    if ((threadIdx.x & 63) == 0) wsum[threadIdx.x >> 6] = s;
    __syncthreads();
    if (threadIdx.x == 0) {
        float t = 0.f;
#pragma unroll
        for (int k = 0; k < 16; ++k) t += wsum[k];
        out[0] = t * scale;
    }
}

extern "C" void kernel_launch(void* const* d_in, const int* in_sizes, int n_in,
                              void* d_out, int out_size, void* d_ws, size_t ws_size,
                              hipStream_t stream) {
    const float* pref  = (const float*)d_in[0];
    const float* ppred = (const float*)d_in[1];
    float* out = (float*)d_out;

    const int B  = in_sizes[0] / (NPTS * 3);
    const int NQ = B * NPTS;
    const int NG = NQ / 4;                 // query groups == waves
    const float scale = 1.0f / ((float)NQ * (float)KNN);

    char* ws = (char*)d_ws;
    float4* wxyzw = (float4*)ws;                                   // B*N*16
    int*    widx  = (int*)   (ws + (size_t)B * NPTS * 16);         // B*N*4
    float4* wbb   = (float4*)(ws + (size_t)B * NPTS * 20);         // B*64*2*16
    float*  partials = (float*)(ws + (size_t)B * NPTS * 20 + (size_t)B * NBLK * 32);

    sort_kernel<<<dim3(B), dim3(1024), 0, stream>>>(pref, wxyzw, widx, wbb);
    knn_main_kernel<<<dim3(NG / 4), dim3(256), 0, stream>>>(ppred, wxyzw, widx, wbb, partials, NG);
    reduce_kernel<<<dim3(1), dim3(1024), 0, stream>>>(partials, NG, out, scale);
}

// Round 16
// 80.225 us; speedup vs baseline: 1.6995x; 1.6538x over previous
//
#include <hip/hip_runtime.h>

#define NPTS  4096
#define KNN   16
#define K1    17            // KNN + self
#define NBLK  64            // candidate blocks per batch == wave width
#define CELLS 4096          // 16^3 Morton cells
#define WPB   16            // waves (queries) per 1024-thread block
#define EPSF  1e-10f

__device__ __forceinline__ unsigned umin_(unsigned a, unsigned b) { return a < b ? a : b; }
__device__ __forceinline__ unsigned umax_(unsigned a, unsigned b) { return a < b ? b : a; }
__device__ __forceinline__ unsigned rdlane(unsigned v, int l) {
    return (unsigned)__builtin_amdgcn_readlane((int)v, l);
}

// cheap cross-lane primitives (DPP = VALU, ds_swizzle = DS pipe, shfl = ds_permute)
#define DPP_XOR1(v)  ((unsigned)__builtin_amdgcn_update_dpp(0, (int)(v), 0xB1, 0xF, 0xF, true))
#define DPP_XOR2(v)  ((unsigned)__builtin_amdgcn_update_dpp(0, (int)(v), 0x4E, 0xF, 0xF, true))
#define SWZ_XOR(v,J) ((unsigned)__builtin_amdgcn_ds_swizzle((int)(v), ((J) << 10) | 0x1F))
#define DPP_SHR1(v)  ((unsigned)__builtin_amdgcn_update_dpp(0, (int)(v), 0x111, 0xF, 0xF, true))
#define DPPF_SHR(vf, CTRL) __uint_as_float((unsigned)__builtin_amdgcn_update_dpp(0, (int)__float_as_uint(vf), CTRL, 0xF, 0xF, true))
#define LXOR1(v)  DPP_XOR1(v)
#define LXOR2(v)  DPP_XOR2(v)
#define LXOR4(v)  SWZ_XOR(v, 4)
#define LXOR8(v)  SWZ_XOR(v, 8)
#define LXOR16(v) SWZ_XOR(v, 16)
#define LXOR32(v) ((unsigned)__shfl_xor((int)(v), 32))

// one compare-exchange stage applied to BOTH sort chains (ILP)
#define BSTEP(K, XORF) do {                                                   \
    unsigned o1_ = XORF(arr), o2_ = XORF(bk);                                 \
    bool tm_ = (((lane & (J_)) == 0) == ((lane & (K)) == 0));                 \
    unsigned mn1_ = umin_(arr, o1_), mx1_ = umax_(arr, o1_);                  \
    unsigned mn2_ = umin_(bk, o2_),  mx2_ = umax_(bk, o2_);                   \
    arr = tm_ ? mn1_ : mx1_; bk = tm_ ? mn2_ : mx2_;                          \
} while (0)

// spread 4 bits to positions 0,3,6,9
__device__ __forceinline__ unsigned sp4(int v) {
    unsigned x = (unsigned)v;
    return (x & 1u) | ((x & 2u) << 2) | ((x & 4u) << 4) | ((x & 8u) << 6);
}

// ---- Kernel 1: per-batch counting sort by 12-bit Morton cell + per-64-block
// bboxes (proven R10 version). Sort is permutation-only; bboxes true min/max.
__global__ __launch_bounds__(1024) void sort_kernel(
    const float* __restrict__ pref,
    float4* __restrict__ wxyzw, int* __restrict__ widx, float4* __restrict__ wbb)
{
    __shared__ unsigned hist[CELLS];          // 16 KB
    __shared__ unsigned short cells[NPTS];    // 8 KB
    __shared__ unsigned wofs[16];
    const int tid  = threadIdx.x;
    const int lane = tid & 63, w = tid >> 6;
    const int b = blockIdx.x;
    const float* prb = pref + (size_t)b * NPTS * 3;
    const size_t base = (size_t)b * NPTS;

    for (int t = tid; t < CELLS; t += 1024) hist[t] = 0u;
    __syncthreads();

    for (int p = tid; p < NPTS; p += 1024) {
        float x = prb[3 * p + 0], y = prb[3 * p + 1], z = prb[3 * p + 2];
        int cx = min(15, max(0, (int)((x + 4.0f) * 2.0f)));
        int cy = min(15, max(0, (int)((y + 4.0f) * 2.0f)));
        int cz = min(15, max(0, (int)((z + 4.0f) * 2.0f)));
        unsigned m = sp4(cx) | (sp4(cy) << 1) | (sp4(cz) << 2);
        cells[p] = (unsigned short)m;
        atomicAdd(&hist[m], 1u);
    }
    __syncthreads();

    unsigned l0 = hist[4 * tid + 0], l1 = hist[4 * tid + 1];
    unsigned l2 = hist[4 * tid + 2], l3 = hist[4 * tid + 3];
    unsigned s = l0 + l1 + l2 + l3;
    unsigned run = s;
#pragma unroll
    for (int d = 1; d < 64; d <<= 1) {
        unsigned o = __shfl_up(run, d);
        if (lane >= d) run += o;
    }
    if (lane == 63) wofs[w] = run;
    __syncthreads();
    if (tid == 0) {
        unsigned acc = 0;
#pragma unroll
        for (int k = 0; k < 16; ++k) { unsigned t2 = wofs[k]; wofs[k] = acc; acc += t2; }
    }
    __syncthreads();
    unsigned excl = wofs[w] + run - s;
    hist[4 * tid + 0] = excl;
    hist[4 * tid + 1] = excl + l0;
    hist[4 * tid + 2] = excl + l0 + l1;
    hist[4 * tid + 3] = excl + l0 + l1 + l2;
    __syncthreads();

    for (int p = tid; p < NPTS; p += 1024) {
        unsigned c = cells[p];
        unsigned pos = atomicAdd(&hist[c], 1u);
        wxyzw[base + pos] = make_float4(prb[3 * p + 0], prb[3 * p + 1], prb[3 * p + 2], 0.f);
        widx[base + pos]  = p;
    }
    __syncthreads();

#pragma unroll
    for (int rep = 0; rep < 4; ++rep) {
        int blk = w + rep * 16;
        float4 c = wxyzw[base + blk * 64 + lane];
        float mnx = c.x, mxx = c.x, mny = c.y, mxy2 = c.y, mnz = c.z, mxz = c.z;
#pragma unroll
        for (int d = 32; d > 0; d >>= 1) {
            mnx  = fminf(mnx,  __shfl_xor(mnx,  d));
            mxx  = fmaxf(mxx,  __shfl_xor(mxx,  d));
            mny  = fminf(mny,  __shfl_xor(mny,  d));
            mxy2 = fmaxf(mxy2, __shfl_xor(mxy2, d));
            mnz  = fminf(mnz,  __shfl_xor(mnz,  d));
            mxz  = fmaxf(mxz,  __shfl_xor(mxz,  d));
        }
        if (lane == 0) {
            wbb[((size_t)b * NBLK + blk) * 2 + 0] = make_float4(mnx, mny, mnz, 0.f);
            wbb[((size_t)b * NBLK + blk) * 2 + 1] = make_float4(mxx, mxy2, mxz, 0.f);
        }
    }
}

// DPP-based insertion of broadcast key kk_ into lane-sliced sorted arr
#define EVENTS(KEY) do {                                                      \
    unsigned long long m_ = __ballot((KEY) < thr);                            \
    if (m_) {                                                                 \
        do {                                                                  \
            int l_ = __ffsll(m_) - 1;                                         \
            m_ &= m_ - 1;                                                     \
            unsigned kk_ = rdlane(KEY, l_);                                   \
            unsigned long long lt_ = __ballot(arr < kk_) & 0x1FFFFull;        \
            int pos_ = __popcll(lt_);                                         \
            unsigned up_ = DPP_SHR1(arr);                                     \
            unsigned a15_ = rdlane(arr, 15);                                  \
            up_ = (lane == 16) ? a15_ : up_;                                  \
            arr = (lane == pos_) ? kk_ : ((lane > pos_) ? up_ : arr);         \
        } while (m_);                                                         \
        thr = rdlane(arr, K1 - 1);                                            \
    } } while (0)

// ---- Kernel 2: R10 algorithm verbatim, but 1024-thread blocks (16 waves,
// one query each). Blocks are hash-permuted; the 16 waves of a block take
// CONSECUTIVE sorted positions (correlated durations -> minimal max-of-16
// retirement coupling; R6 showed this geometry reaches ~62% occupancy).
__global__ __launch_bounds__(1024) void knn_main_kernel(
    const float* __restrict__ ppred,
    const float4* __restrict__ wxyzw, const int* __restrict__ widx,
    const float4* __restrict__ wbb, float* __restrict__ partials, int NQ)
{
    const int lane = threadIdx.x & 63;
    const int w    = threadIdx.x >> 6;
    const int ngrp = NQ / WPB;
    // hash-permute at block granularity (odd multiplier mod pow2 = bijection)
    const int g = ((ngrp & (ngrp - 1)) == 0)
                ? (int)(((unsigned)blockIdx.x * 26765u) & (unsigned)(ngrp - 1))
                : blockIdx.x;
    const int q = g * WPB + w;                 // consecutive positions in block

    const int b = q >> 12;
    const int p = q & (NPTS - 1);              // sorted position = query
    const size_t base = (size_t)b * NPTS;
    const int p0 = p & ~63, ownblk = p >> 6;

    const float4 qc = wxyzw[base + p];         // uniform -> broadcast
    const float qx = qc.x, qy = qc.y, qz = qc.z;

    // own-block candidate keys (self d2 == +0.0 -> key = p = minimum)
    unsigned arr;
    {
        float4 c = wxyzw[base + p0 + lane];
        float dx = c.x - qx, dy = c.y - qy, dz = c.z - qz;
        float d2 = dx * dx + dy * dy + dz * dz;
        arr = (__float_as_uint(d2) & 0xFFFFF000u) | (unsigned)(p0 + lane);
    }
    // bbox lower-bound keys: same truncation as real keys; blk in the index
    // field (blk <= any j in block) => bkey <= every real key in the block.
    unsigned bk;
    {
        float4 mn4 = wbb[((size_t)b * NBLK + lane) * 2 + 0];
        float4 mx4 = wbb[((size_t)b * NBLK + lane) * 2 + 1];
        float ddx = fmaxf(fmaxf(mn4.x - qx, qx - mx4.x), 0.0f);
        float ddy = fmaxf(fmaxf(mn4.y - qy, qy - mx4.y), 0.0f);
        float ddz = fmaxf(fmaxf(mn4.z - qz, qz - mx4.z), 0.0f);
        float bd2 = ddx * ddx + ddy * ddy + ddz * ddz;
        bk = (__float_as_uint(bd2) & 0xFFFFF000u) | (unsigned)lane;
        bk = (lane == ownblk) ? 0xFFFFFFFFu : bk;   // sentinel: never walked
    }

    // joint bitonic sort of arr and bk (ascending), ILP'd through one network
    {
        int J_;
        J_ = 1;  BSTEP(2,  LXOR1);
        J_ = 2;  BSTEP(4,  LXOR2);  J_ = 1; BSTEP(4,  LXOR1);
        J_ = 4;  BSTEP(8,  LXOR4);  J_ = 2; BSTEP(8,  LXOR2);  J_ = 1; BSTEP(8,  LXOR1);
        J_ = 8;  BSTEP(16, LXOR8);  J_ = 4; BSTEP(16, LXOR4);  J_ = 2; BSTEP(16, LXOR2);  J_ = 1; BSTEP(16, LXOR1);
        J_ = 16; BSTEP(32, LXOR16); J_ = 8; BSTEP(32, LXOR8);  J_ = 4; BSTEP(32, LXOR4);  J_ = 2; BSTEP(32, LXOR2); J_ = 1; BSTEP(32, LXOR1);
        J_ = 32; BSTEP(64, LXOR32); J_ = 16; BSTEP(64, LXOR16); J_ = 8; BSTEP(64, LXOR8); J_ = 4; BSTEP(64, LXOR4); J_ = 2; BSTEP(64, LXOR2); J_ = 1; BSTEP(64, LXOR1);
    }
    unsigned thr = rdlane(arr, K1 - 1);

    // ordered walk: blocks by ascending lower bound; break = prune rest (exact:
    // truncation is monotone, bkey <= real keys, thr only decreases).
    int k = 0;
    unsigned bcur = rdlane(bk, 0);
    bool have = (bcur < thr);
    float4 cur;
    if (have) cur = wxyzw[base + (int)(bcur & 0xFFFu) * 64 + lane];
    while (have) {
        unsigned bnext = rdlane(bk, k + 1);
        bool pf = (bnext < thr);               // prefetch decision (conservative)
        float4 nxt;
        if (pf) nxt = wxyzw[base + (int)(bnext & 0xFFFu) * 64 + lane];
        int jbase = (int)(bcur & 0xFFFu) * 64;
        float dx = cur.x - qx, dy = cur.y - qy, dz = cur.z - qz;
        float d2 = dx * dx + dy * dy + dz * dz;
        unsigned key = (__float_as_uint(d2) & 0xFFFFF000u) | (unsigned)(jbase + lane);
        EVENTS(key);                           // tightens thr
        ++k;
        bcur = bnext;
        have = (bcur < thr);                   // thr only decreased: pf false => have false
        cur = nxt;
    }

    // Epilogue: lanes 1..16 hold the 16 nearest neighbors (lane 0 = self).
    const float* ppb = ppred + (size_t)b * NPTS * 3;
    const int iorig = widx[base + p];
    float s = 0.f;
    if (lane >= 1 && lane <= KNN) {
        int js = (int)(arr & 0xFFFu);
        float4 rc = wxyzw[base + js];
        float rx = rc.x - qx, ry = rc.y - qy, rz = rc.z - qz;
        float dref = sqrtf(rx * rx + ry * ry + rz * rz);
        int nj = widx[base + js];
        float px = ppb[3 * iorig + 0], py = ppb[3 * iorig + 1], pz = ppb[3 * iorig + 2];
        float ax = ppb[3 * nj + 0] - px;
        float ay = ppb[3 * nj + 1] - py;
        float az = ppb[3 * nj + 2] - pz;
        float dpred = sqrtf(ax * ax + ay * ay + az * az);
        s = fmaxf(dpred / (dref + EPSF) - 1.0f, 0.0f);
    }
    // DPP prefix-add within rows of 16; lanes 0..16 hold all nonzeros.
    s += DPPF_SHR(s, 0x111);
    s += DPPF_SHR(s, 0x112);
    s += DPPF_SHR(s, 0x114);
    s += DPPF_SHR(s, 0x118);
    float t15 = __uint_as_float(rdlane(__float_as_uint(s), 15));
    float t16 = __uint_as_float(rdlane(__float_as_uint(s), 16));
    if (lane == 0) partials[q] = t15 + t16;
}

// ---- Kernel 3: deterministic single-block final reduction.
__global__ __launch_bounds__(1024) void reduce_kernel(
    const float* __restrict__ partials, int n, float* __restrict__ out, float scale)
{
    __shared__ float wsum[16];
    float s = 0.f;
    for (int idx = threadIdx.x; idx < n; idx += 1024) s += partials[idx];
    for (int off = 32; off > 0; off >>= 1) s += __shfl_down(s, off);
    if ((threadIdx.x & 63) == 0) wsum[threadIdx.x >> 6] = s;
    __syncthreads();
    if (threadIdx.x == 0) {
        float t = 0.f;
#pragma unroll
        for (int k = 0; k < 16; ++k) t += wsum[k];
        out[0] = t * scale;
    }
}

extern "C" void kernel_launch(void* const* d_in, const int* in_sizes, int n_in,
                              void* d_out, int out_size, void* d_ws, size_t ws_size,
                              hipStream_t stream) {
    const float* pref  = (const float*)d_in[0];
    const float* ppred = (const float*)d_in[1];
    float* out = (float*)d_out;

    const int B  = in_sizes[0] / (NPTS * 3);
    const int NQ = B * NPTS;
    const float scale = 1.0f / ((float)NQ * (float)KNN);

    char* ws = (char*)d_ws;
    float4* wxyzw = (float4*)ws;                                   // B*N*16
    int*    widx  = (int*)   (ws + (size_t)B * NPTS * 16);         // B*N*4
    float4* wbb   = (float4*)(ws + (size_t)B * NPTS * 20);         // B*64*2*16
    float*  partials = (float*)(ws + (size_t)B * NPTS * 20 + (size_t)B * NBLK * 32);

    sort_kernel<<<dim3(B), dim3(1024), 0, stream>>>(pref, wxyzw, widx, wbb);
    knn_main_kernel<<<dim3(NQ / WPB), dim3(1024), 0, stream>>>(ppred, wxyzw, widx, wbb, partials, NQ);
    reduce_kernel<<<dim3(1), dim3(1024), 0, stream>>>(partials, NQ, out, scale);
}

// Round 17
// 77.495 us; speedup vs baseline: 1.7593x; 1.0352x over previous
//
#include <hip/hip_runtime.h>

#define NPTS  4096
#define KNN   16
#define K1    17            // KNN + self
#define NBLK  64            // candidate blocks per batch == wave width
#define CELLS 4096          // 16^3 Morton cells
#define GQ    2             // queries per wave, processed SEQUENTIALLY
#define EPSF  1e-10f

__device__ __forceinline__ unsigned umin_(unsigned a, unsigned b) { return a < b ? a : b; }
__device__ __forceinline__ unsigned umax_(unsigned a, unsigned b) { return a < b ? b : a; }
__device__ __forceinline__ unsigned rdlane(unsigned v, int l) {
    return (unsigned)__builtin_amdgcn_readlane((int)v, l);
}

// cheap cross-lane primitives (DPP = VALU, ds_swizzle = DS pipe, shfl = ds_permute)
#define DPP_XOR1(v)  ((unsigned)__builtin_amdgcn_update_dpp(0, (int)(v), 0xB1, 0xF, 0xF, true))
#define DPP_XOR2(v)  ((unsigned)__builtin_amdgcn_update_dpp(0, (int)(v), 0x4E, 0xF, 0xF, true))
#define SWZ_XOR(v,J) ((unsigned)__builtin_amdgcn_ds_swizzle((int)(v), ((J) << 10) | 0x1F))
#define DPP_SHR1(v)  ((unsigned)__builtin_amdgcn_update_dpp(0, (int)(v), 0x111, 0xF, 0xF, true))
#define DPPF_SHR(vf, CTRL) __uint_as_float((unsigned)__builtin_amdgcn_update_dpp(0, (int)__float_as_uint(vf), CTRL, 0xF, 0xF, true))
#define LXOR1(v)  DPP_XOR1(v)
#define LXOR2(v)  DPP_XOR2(v)
#define LXOR4(v)  SWZ_XOR(v, 4)
#define LXOR8(v)  SWZ_XOR(v, 8)
#define LXOR16(v) SWZ_XOR(v, 16)
#define LXOR32(v) ((unsigned)__shfl_xor((int)(v), 32))

// one compare-exchange stage applied to BOTH sort chains (ILP)
#define BSTEP(K, XORF) do {                                                   \
    unsigned o1_ = XORF(arr), o2_ = XORF(bk);                                 \
    bool tm_ = (((lane & (J_)) == 0) == ((lane & (K)) == 0));                 \
    unsigned mn1_ = umin_(arr, o1_), mx1_ = umax_(arr, o1_);                  \
    unsigned mn2_ = umin_(bk, o2_),  mx2_ = umax_(bk, o2_);                   \
    arr = tm_ ? mn1_ : mx1_; bk = tm_ ? mn2_ : mx2_;                          \
} while (0)

// spread 4 bits to positions 0,3,6,9
__device__ __forceinline__ unsigned sp4(int v) {
    unsigned x = (unsigned)v;
    return (x & 1u) | ((x & 2u) << 2) | ((x & 4u) << 4) | ((x & 8u) << 6);
}

// ---- Kernel 1: per-batch counting sort by 12-bit Morton cell + per-64-block
// bboxes (proven R10 version). Sort is permutation-only; bboxes true min/max.
__global__ __launch_bounds__(1024) void sort_kernel(
    const float* __restrict__ pref,
    float4* __restrict__ wxyzw, int* __restrict__ widx, float4* __restrict__ wbb)
{
    __shared__ unsigned hist[CELLS];          // 16 KB
    __shared__ unsigned short cells[NPTS];    // 8 KB
    __shared__ unsigned wofs[16];
    const int tid  = threadIdx.x;
    const int lane = tid & 63, w = tid >> 6;
    const int b = blockIdx.x;
    const float* prb = pref + (size_t)b * NPTS * 3;
    const size_t base = (size_t)b * NPTS;

    for (int t = tid; t < CELLS; t += 1024) hist[t] = 0u;
    __syncthreads();

    for (int p = tid; p < NPTS; p += 1024) {
        float x = prb[3 * p + 0], y = prb[3 * p + 1], z = prb[3 * p + 2];
        int cx = min(15, max(0, (int)((x + 4.0f) * 2.0f)));
        int cy = min(15, max(0, (int)((y + 4.0f) * 2.0f)));
        int cz = min(15, max(0, (int)((z + 4.0f) * 2.0f)));
        unsigned m = sp4(cx) | (sp4(cy) << 1) | (sp4(cz) << 2);
        cells[p] = (unsigned short)m;
        atomicAdd(&hist[m], 1u);
    }
    __syncthreads();

    unsigned l0 = hist[4 * tid + 0], l1 = hist[4 * tid + 1];
    unsigned l2 = hist[4 * tid + 2], l3 = hist[4 * tid + 3];
    unsigned s = l0 + l1 + l2 + l3;
    unsigned run = s;
#pragma unroll
    for (int d = 1; d < 64; d <<= 1) {
        unsigned o = __shfl_up(run, d);
        if (lane >= d) run += o;
    }
    if (lane == 63) wofs[w] = run;
    __syncthreads();
    if (tid == 0) {
        unsigned acc = 0;
#pragma unroll
        for (int k = 0; k < 16; ++k) { unsigned t2 = wofs[k]; wofs[k] = acc; acc += t2; }
    }
    __syncthreads();
    unsigned excl = wofs[w] + run - s;
    hist[4 * tid + 0] = excl;
    hist[4 * tid + 1] = excl + l0;
    hist[4 * tid + 2] = excl + l0 + l1;
    hist[4 * tid + 3] = excl + l0 + l1 + l2;
    __syncthreads();

    for (int p = tid; p < NPTS; p += 1024) {
        unsigned c = cells[p];
        unsigned pos = atomicAdd(&hist[c], 1u);
        wxyzw[base + pos] = make_float4(prb[3 * p + 0], prb[3 * p + 1], prb[3 * p + 2], 0.f);
        widx[base + pos]  = p;
    }
    __syncthreads();

#pragma unroll
    for (int rep = 0; rep < 4; ++rep) {
        int blk = w + rep * 16;
        float4 c = wxyzw[base + blk * 64 + lane];
        float mnx = c.x, mxx = c.x, mny = c.y, mxy2 = c.y, mnz = c.z, mxz = c.z;
#pragma unroll
        for (int d = 32; d > 0; d >>= 1) {
            mnx  = fminf(mnx,  __shfl_xor(mnx,  d));
            mxx  = fmaxf(mxx,  __shfl_xor(mxx,  d));
            mny  = fminf(mny,  __shfl_xor(mny,  d));
            mxy2 = fmaxf(mxy2, __shfl_xor(mxy2, d));
            mnz  = fminf(mnz,  __shfl_xor(mnz,  d));
            mxz  = fmaxf(mxz,  __shfl_xor(mxz,  d));
        }
        if (lane == 0) {
            wbb[((size_t)b * NBLK + blk) * 2 + 0] = make_float4(mnx, mny, mnz, 0.f);
            wbb[((size_t)b * NBLK + blk) * 2 + 1] = make_float4(mxx, mxy2, mxz, 0.f);
        }
    }
}

// DPP-based insertion of broadcast key kk_ into lane-sliced sorted arr
#define EVENTS(KEY) do {                                                      \
    unsigned long long m_ = __ballot((KEY) < thr);                            \
    if (m_) {                                                                 \
        do {                                                                  \
            int l_ = __ffsll(m_) - 1;                                         \
            m_ &= m_ - 1;                                                     \
            unsigned kk_ = rdlane(KEY, l_);                                   \
            unsigned long long lt_ = __ballot(arr < kk_) & 0x1FFFFull;        \
            int pos_ = __popcll(lt_);                                         \
            unsigned up_ = DPP_SHR1(arr);                                     \
            unsigned a15_ = rdlane(arr, 15);                                  \
            up_ = (lane == 16) ? a15_ : up_;                                  \
            arr = (lane == pos_) ? kk_ : ((lane > pos_) ? up_ : arr);         \
        } while (m_);                                                         \
        thr = rdlane(arr, K1 - 1);                                            \
    } } while (0)

// ---- Kernel 2: GQ hash-mixed queries per wave, processed STRICTLY
// SEQUENTIALLY (R10 inner loop verbatim per query; zero coupling). Halves
// the wave count to beat the ~600 waves/us global wave-dispatch cap while
// keeping per-query work identical.
__global__ __launch_bounds__(256, 8) void knn_main_kernel(
    const float* __restrict__ ppred,
    const float4* __restrict__ wxyzw, const int* __restrict__ widx,
    const float4* __restrict__ wbb, float* __restrict__ partials, int NQ)
{
    const int lane = threadIdx.x & 63;
    const int wv   = blockIdx.x * 4 + (threadIdx.x >> 6);
    const bool pow2 = (NQ & (NQ - 1)) == 0;

#pragma unroll 1
    for (int t = 0; t < GQ; ++t) {
        const int qid = wv * GQ + t;
        // odd multiplier mod pow2 is a bijection; mixes spatial regions
        const int q = pow2 ? (int)(((unsigned)qid * 26765u) & (unsigned)(NQ - 1)) : qid;

        const int b = q >> 12;
        const int p = q & (NPTS - 1);              // sorted position = query
        const size_t base = (size_t)b * NPTS;
        const int p0 = p & ~63, ownblk = p >> 6;

        const float4 qc = wxyzw[base + p];         // uniform -> broadcast
        const float qx = qc.x, qy = qc.y, qz = qc.z;

        // own-block candidate keys (self d2 == +0.0 -> key = p = minimum)
        unsigned arr;
        {
            float4 c = wxyzw[base + p0 + lane];
            float dx = c.x - qx, dy = c.y - qy, dz = c.z - qz;
            float d2 = dx * dx + dy * dy + dz * dz;
            arr = (__float_as_uint(d2) & 0xFFFFF000u) | (unsigned)(p0 + lane);
        }
        // bbox lower-bound keys: same truncation as real keys; blk in the
        // index field (blk <= any j in block) => bkey <= every real key.
        unsigned bk;
        {
            float4 mn4 = wbb[((size_t)b * NBLK + lane) * 2 + 0];
            float4 mx4 = wbb[((size_t)b * NBLK + lane) * 2 + 1];
            float ddx = fmaxf(fmaxf(mn4.x - qx, qx - mx4.x), 0.0f);
            float ddy = fmaxf(fmaxf(mn4.y - qy, qy - mx4.y), 0.0f);
            float ddz = fmaxf(fmaxf(mn4.z - qz, qz - mx4.z), 0.0f);
            float bd2 = ddx * ddx + ddy * ddy + ddz * ddz;
            bk = (__float_as_uint(bd2) & 0xFFFFF000u) | (unsigned)lane;
            bk = (lane == ownblk) ? 0xFFFFFFFFu : bk;   // sentinel: never walked
        }

        // joint bitonic sort of arr and bk (ascending), ILP'd
        {
            int J_;
            J_ = 1;  BSTEP(2,  LXOR1);
            J_ = 2;  BSTEP(4,  LXOR2);  J_ = 1; BSTEP(4,  LXOR1);
            J_ = 4;  BSTEP(8,  LXOR4);  J_ = 2; BSTEP(8,  LXOR2);  J_ = 1; BSTEP(8,  LXOR1);
            J_ = 8;  BSTEP(16, LXOR8);  J_ = 4; BSTEP(16, LXOR4);  J_ = 2; BSTEP(16, LXOR2);  J_ = 1; BSTEP(16, LXOR1);
            J_ = 16; BSTEP(32, LXOR16); J_ = 8; BSTEP(32, LXOR8);  J_ = 4; BSTEP(32, LXOR4);  J_ = 2; BSTEP(32, LXOR2); J_ = 1; BSTEP(32, LXOR1);
            J_ = 32; BSTEP(64, LXOR32); J_ = 16; BSTEP(64, LXOR16); J_ = 8; BSTEP(64, LXOR8); J_ = 4; BSTEP(64, LXOR4); J_ = 2; BSTEP(64, LXOR2); J_ = 1; BSTEP(64, LXOR1);
        }
        unsigned thr = rdlane(arr, K1 - 1);

        // ordered walk: blocks by ascending lower bound; break = prune (exact).
        int k = 0;
        unsigned bcur = rdlane(bk, 0);
        bool have = (bcur < thr);
        float4 cur;
        if (have) cur = wxyzw[base + (int)(bcur & 0xFFFu) * 64 + lane];
        while (have) {
            unsigned bnext = rdlane(bk, k + 1);
            bool pf = (bnext < thr);               // conservative prefetch decision
            float4 nxt;
            if (pf) nxt = wxyzw[base + (int)(bnext & 0xFFFu) * 64 + lane];
            int jbase = (int)(bcur & 0xFFFu) * 64;
            float dx = cur.x - qx, dy = cur.y - qy, dz = cur.z - qz;
            float d2 = dx * dx + dy * dy + dz * dz;
            unsigned key = (__float_as_uint(d2) & 0xFFFFF000u) | (unsigned)(jbase + lane);
            EVENTS(key);                           // tightens thr
            ++k;
            bcur = bnext;
            have = (bcur < thr);                   // thr only decreased
            cur = nxt;
        }

        // Epilogue: lanes 1..16 hold the 16 nearest neighbors (lane 0 = self).
        const float* ppb = ppred + (size_t)b * NPTS * 3;
        const int iorig = widx[base + p];
        float s = 0.f;
        if (lane >= 1 && lane <= KNN) {
            int js = (int)(arr & 0xFFFu);
            float4 rc = wxyzw[base + js];
            float rx = rc.x - qx, ry = rc.y - qy, rz = rc.z - qz;
            float dref = sqrtf(rx * rx + ry * ry + rz * rz);
            int nj = widx[base + js];
            float px = ppb[3 * iorig + 0], py = ppb[3 * iorig + 1], pz = ppb[3 * iorig + 2];
            float ax = ppb[3 * nj + 0] - px;
            float ay = ppb[3 * nj + 1] - py;
            float az = ppb[3 * nj + 2] - pz;
            float dpred = sqrtf(ax * ax + ay * ay + az * az);
            s = fmaxf(dpred / (dref + EPSF) - 1.0f, 0.0f);
        }
        // DPP prefix-add within rows of 16; lanes 0..16 hold all nonzeros.
        s += DPPF_SHR(s, 0x111);
        s += DPPF_SHR(s, 0x112);
        s += DPPF_SHR(s, 0x114);
        s += DPPF_SHR(s, 0x118);
        float t15 = __uint_as_float(rdlane(__float_as_uint(s), 15));
        float t16 = __uint_as_float(rdlane(__float_as_uint(s), 16));
        if (lane == 0) partials[q] = t15 + t16;
    }
}

// ---- Kernel 3: deterministic single-block final reduction.
__global__ __launch_bounds__(1024) void reduce_kernel(
    const float* __restrict__ partials, int n, float* __restrict__ out, float scale)
{
    __shared__ float wsum[16];
    float s = 0.f;
    for (int idx = threadIdx.x; idx < n; idx += 1024) s += partials[idx];
    for (int off = 32; off > 0; off >>= 1) s += __shfl_down(s, off);
    if ((threadIdx.x & 63) == 0) wsum[threadIdx.x >> 6] = s;
    __syncthreads();
    if (threadIdx.x == 0) {
        float t = 0.f;
#pragma unroll
        for (int k = 0; k < 16; ++k) t += wsum[k];
        out[0] = t * scale;
    }
}

extern "C" void kernel_launch(void* const* d_in, const int* in_sizes, int n_in,
                              void* d_out, int out_size, void* d_ws, size_t ws_size,
                              hipStream_t stream) {
    const float* pref  = (const float*)d_in[0];
    const float* ppred = (const float*)d_in[1];
    float* out = (float*)d_out;

    const int B  = in_sizes[0] / (NPTS * 3);
    const int NQ = B * NPTS;
    const int nblocks = NQ / (GQ * 4);     // 4 waves/block, GQ queries/wave
    const float scale = 1.0f / ((float)NQ * (float)KNN);

    char* ws = (char*)d_ws;
    float4* wxyzw = (float4*)ws;                                   // B*N*16
    int*    widx  = (int*)   (ws + (size_t)B * NPTS * 16);         // B*N*4
    float4* wbb   = (float4*)(ws + (size_t)B * NPTS * 20);         // B*64*2*16
    float*  partials = (float*)(ws + (size_t)B * NPTS * 20 + (size_t)B * NBLK * 32);

    sort_kernel<<<dim3(B), dim3(1024), 0, stream>>>(pref, wxyzw, widx, wbb);
    knn_main_kernel<<<dim3(nblocks), dim3(256), 0, stream>>>(ppred, wxyzw, widx, wbb, partials, NQ);
    reduce_kernel<<<dim3(1), dim3(1024), 0, stream>>>(partials, NQ, out, scale);
}

// Round 18
// 75.680 us; speedup vs baseline: 1.8015x; 1.0240x over previous
//
#include <hip/hip_runtime.h>

#define NPTS  4096
#define KNN   16
#define K1    17            // KNN + self
#define NBLK  64            // candidate blocks per batch == wave width
#define CELLS 4096          // 16^3 Morton cells
#define EPSF  1e-10f

__device__ __forceinline__ unsigned umin_(unsigned a, unsigned b) { return a < b ? a : b; }
__device__ __forceinline__ unsigned umax_(unsigned a, unsigned b) { return a < b ? b : a; }
__device__ __forceinline__ unsigned rdlane(unsigned v, int l) {
    return (unsigned)__builtin_amdgcn_readlane((int)v, l);
}

// cheap cross-lane primitives (DPP = VALU, ds_swizzle = DS pipe, shfl = ds_permute)
#define DPP_XOR1(v)  ((unsigned)__builtin_amdgcn_update_dpp(0, (int)(v), 0xB1, 0xF, 0xF, true))
#define DPP_XOR2(v)  ((unsigned)__builtin_amdgcn_update_dpp(0, (int)(v), 0x4E, 0xF, 0xF, true))
#define SWZ_XOR(v,J) ((unsigned)__builtin_amdgcn_ds_swizzle((int)(v), ((J) << 10) | 0x1F))
#define DPP_SHR1(v)  ((unsigned)__builtin_amdgcn_update_dpp(0, (int)(v), 0x111, 0xF, 0xF, true))
#define DPPF_SHR(vf, CTRL) __uint_as_float((unsigned)__builtin_amdgcn_update_dpp(0, (int)__float_as_uint(vf), CTRL, 0xF, 0xF, true))
#define LXOR1(v)  DPP_XOR1(v)
#define LXOR2(v)  DPP_XOR2(v)
#define LXOR4(v)  SWZ_XOR(v, 4)
#define LXOR8(v)  SWZ_XOR(v, 8)
#define LXOR16(v) SWZ_XOR(v, 16)
#define LXOR32(v) ((unsigned)__shfl_xor((int)(v), 32))

// one compare-exchange stage applied to THREE chains:
// arrA ascending, arrB DESCENDING (flipped), bk ascending.
#define BSTEP3(K, XORF) do {                                                  \
    unsigned oa_ = XORF(arrA), ob_ = XORF(arrB), ok_ = XORF(bk);              \
    bool tm_ = (((lane & (J_)) == 0) == ((lane & (K)) == 0));                 \
    arrA = tm_ ? umin_(arrA, oa_) : umax_(arrA, oa_);                         \
    arrB = tm_ ? umax_(arrB, ob_) : umin_(arrB, ob_);                         \
    bk   = tm_ ? umin_(bk,   ok_) : umax_(bk,   ok_);                         \
} while (0)

// one clean stage for a bitonic sequence (ascending), single chain
#define CSTEP(J, XORF) do {                                                   \
    unsigned o_ = XORF(arr);                                                  \
    arr = ((lane & (J)) == 0) ? umin_(arr, o_) : umax_(arr, o_);              \
} while (0)

// spread 4 bits to positions 0,3,6,9
__device__ __forceinline__ unsigned sp4(int v) {
    unsigned x = (unsigned)v;
    return (x & 1u) | ((x & 2u) << 2) | ((x & 4u) << 4) | ((x & 8u) << 6);
}

// ---- Kernel 1: per-batch counting sort by 12-bit Morton cell + per-64-block
// bboxes (proven R10 version). Sort is permutation-only; bboxes true min/max.
__global__ __launch_bounds__(1024) void sort_kernel(
    const float* __restrict__ pref,
    float4* __restrict__ wxyzw, int* __restrict__ widx, float4* __restrict__ wbb)
{
    __shared__ unsigned hist[CELLS];          // 16 KB
    __shared__ unsigned short cells[NPTS];    // 8 KB
    __shared__ unsigned wofs[16];
    const int tid  = threadIdx.x;
    const int lane = tid & 63, w = tid >> 6;
    const int b = blockIdx.x;
    const float* prb = pref + (size_t)b * NPTS * 3;
    const size_t base = (size_t)b * NPTS;

    for (int t = tid; t < CELLS; t += 1024) hist[t] = 0u;
    __syncthreads();

    for (int p = tid; p < NPTS; p += 1024) {
        float x = prb[3 * p + 0], y = prb[3 * p + 1], z = prb[3 * p + 2];
        int cx = min(15, max(0, (int)((x + 4.0f) * 2.0f)));
        int cy = min(15, max(0, (int)((y + 4.0f) * 2.0f)));
        int cz = min(15, max(0, (int)((z + 4.0f) * 2.0f)));
        unsigned m = sp4(cx) | (sp4(cy) << 1) | (sp4(cz) << 2);
        cells[p] = (unsigned short)m;
        atomicAdd(&hist[m], 1u);
    }
    __syncthreads();

    unsigned l0 = hist[4 * tid + 0], l1 = hist[4 * tid + 1];
    unsigned l2 = hist[4 * tid + 2], l3 = hist[4 * tid + 3];
    unsigned s = l0 + l1 + l2 + l3;
    unsigned run = s;
#pragma unroll
    for (int d = 1; d < 64; d <<= 1) {
        unsigned o = __shfl_up(run, d);
        if (lane >= d) run += o;
    }
    if (lane == 63) wofs[w] = run;
    __syncthreads();
    if (tid == 0) {
        unsigned acc = 0;
#pragma unroll
        for (int k = 0; k < 16; ++k) { unsigned t2 = wofs[k]; wofs[k] = acc; acc += t2; }
    }
    __syncthreads();
    unsigned excl = wofs[w] + run - s;
    hist[4 * tid + 0] = excl;
    hist[4 * tid + 1] = excl + l0;
    hist[4 * tid + 2] = excl + l0 + l1;
    hist[4 * tid + 3] = excl + l0 + l1 + l2;
    __syncthreads();

    for (int p = tid; p < NPTS; p += 1024) {
        unsigned c = cells[p];
        unsigned pos = atomicAdd(&hist[c], 1u);
        wxyzw[base + pos] = make_float4(prb[3 * p + 0], prb[3 * p + 1], prb[3 * p + 2], 0.f);
        widx[base + pos]  = p;
    }
    __syncthreads();

#pragma unroll
    for (int rep = 0; rep < 4; ++rep) {
        int blk = w + rep * 16;
        float4 c = wxyzw[base + blk * 64 + lane];
        float mnx = c.x, mxx = c.x, mny = c.y, mxy2 = c.y, mnz = c.z, mxz = c.z;
#pragma unroll
        for (int d = 32; d > 0; d >>= 1) {
            mnx  = fminf(mnx,  __shfl_xor(mnx,  d));
            mxx  = fmaxf(mxx,  __shfl_xor(mxx,  d));
            mny  = fminf(mny,  __shfl_xor(mny,  d));
            mxy2 = fmaxf(mxy2, __shfl_xor(mxy2, d));
            mnz  = fminf(mnz,  __shfl_xor(mnz,  d));
            mxz  = fmaxf(mxz,  __shfl_xor(mxz,  d));
        }
        if (lane == 0) {
            wbb[((size_t)b * NBLK + blk) * 2 + 0] = make_float4(mnx, mny, mnz, 0.f);
            wbb[((size_t)b * NBLK + blk) * 2 + 1] = make_float4(mxx, mxy2, mxz, 0.f);
        }
    }
}

// DPP-based insertion of broadcast key kk_ into lane-sliced sorted arr
#define EVENTS(KEY) do {                                                      \
    unsigned long long m_ = __ballot((KEY) < thr);                            \
    if (m_) {                                                                 \
        do {                                                                  \
            int l_ = __ffsll(m_) - 1;                                         \
            m_ &= m_ - 1;                                                     \
            unsigned kk_ = rdlane(KEY, l_);                                   \
            unsigned long long lt_ = __ballot(arr < kk_) & 0x1FFFFull;        \
            int pos_ = __popcll(lt_);                                         \
            unsigned up_ = DPP_SHR1(arr);                                     \
            unsigned a15_ = rdlane(arr, 15);                                  \
            up_ = (lane == 16) ? a15_ : up_;                                  \
            arr = (lane == pos_) ? kk_ : ((lane > pos_) ? up_ : arr);         \
        } while (m_);                                                         \
        thr = rdlane(arr, K1 - 1);                                            \
    } } while (0)

// ---- Kernel 2: one query per wave (R10 structure), but bootstrap over TWO
// blocks (own + Morton-adjacent p0^64): 3-chain bitonic (A asc, B desc, bk
// asc) + bitonic merge (intra-lane min + 6 clean stages) = exact top-17 of
// 128 candidates before the walk -> tighter thr, ~half the serial events.
__global__ __launch_bounds__(256, 8) void knn_main_kernel(
    const float* __restrict__ ppred,
    const float4* __restrict__ wxyzw, const int* __restrict__ widx,
    const float4* __restrict__ wbb, float* __restrict__ partials, int NQ)
{
    const int lane = threadIdx.x & 63;
    const int wv   = blockIdx.x * 4 + (threadIdx.x >> 6);
    // odd multiplier mod pow2 is a bijection; mixes spatial regions
    const int q = ((NQ & (NQ - 1)) == 0) ? (int)(((unsigned)wv * 26765u) & (unsigned)(NQ - 1)) : wv;

    const int b = q >> 12;
    const int p = q & (NPTS - 1);              // sorted position = query
    const size_t base = (size_t)b * NPTS;
    const int p0 = p & ~63, ownblk = p >> 6;
    const int adjblk = ownblk ^ 1;             // block of p0 ^ 64

    const float4 qc = wxyzw[base + p];         // uniform -> broadcast
    const float qx = qc.x, qy = qc.y, qz = qc.z;

    // 128-candidate bootstrap keys (self d2 == +0.0 -> key = p = minimum)
    unsigned arrA, arrB;
    {
        float4 c1 = wxyzw[base + p0 + lane];
        float4 c2 = wxyzw[base + (p0 ^ 64) + lane];
        float dx = c1.x - qx, dy = c1.y - qy, dz = c1.z - qz;
        float d2 = dx * dx + dy * dy + dz * dz;
        arrA = (__float_as_uint(d2) & 0xFFFFF000u) | (unsigned)(p0 + lane);
        dx = c2.x - qx; dy = c2.y - qy; dz = c2.z - qz;
        d2 = dx * dx + dy * dy + dz * dz;
        arrB = (__float_as_uint(d2) & 0xFFFFF000u) | (unsigned)((p0 ^ 64) + lane);
    }
    // bbox lower-bound keys; sentinel BOTH bootstrap blocks out of the walk
    unsigned bk;
    {
        float4 mn4 = wbb[((size_t)b * NBLK + lane) * 2 + 0];
        float4 mx4 = wbb[((size_t)b * NBLK + lane) * 2 + 1];
        float ddx = fmaxf(fmaxf(mn4.x - qx, qx - mx4.x), 0.0f);
        float ddy = fmaxf(fmaxf(mn4.y - qy, qy - mx4.y), 0.0f);
        float ddz = fmaxf(fmaxf(mn4.z - qz, qz - mx4.z), 0.0f);
        float bd2 = ddx * ddx + ddy * ddy + ddz * ddz;
        bk = (__float_as_uint(bd2) & 0xFFFFF000u) | (unsigned)lane;
        bk = (lane == ownblk || lane == adjblk) ? 0xFFFFFFFFu : bk;
    }

    // 3-chain bitonic network: arrA asc, arrB desc, bk asc
    {
        int J_;
        J_ = 1;  BSTEP3(2,  LXOR1);
        J_ = 2;  BSTEP3(4,  LXOR2);  J_ = 1; BSTEP3(4,  LXOR1);
        J_ = 4;  BSTEP3(8,  LXOR4);  J_ = 2; BSTEP3(8,  LXOR2);  J_ = 1; BSTEP3(8,  LXOR1);
        J_ = 8;  BSTEP3(16, LXOR8);  J_ = 4; BSTEP3(16, LXOR4);  J_ = 2; BSTEP3(16, LXOR2);  J_ = 1; BSTEP3(16, LXOR1);
        J_ = 16; BSTEP3(32, LXOR16); J_ = 8; BSTEP3(32, LXOR8);  J_ = 4; BSTEP3(32, LXOR4);  J_ = 2; BSTEP3(32, LXOR2); J_ = 1; BSTEP3(32, LXOR1);
        J_ = 32; BSTEP3(64, LXOR32); J_ = 16; BSTEP3(64, LXOR16); J_ = 8; BSTEP3(64, LXOR8); J_ = 4; BSTEP3(64, LXOR4); J_ = 2; BSTEP3(64, LXOR2); J_ = 1; BSTEP3(64, LXOR1);
    }
    // bitonic merge: lower-64 of the 128 (bitonic sequence), then 6 cleans
    unsigned arr = umin_(arrA, arrB);
    CSTEP(32, LXOR32);
    CSTEP(16, LXOR16);
    CSTEP(8,  LXOR8);
    CSTEP(4,  LXOR4);
    CSTEP(2,  LXOR2);
    CSTEP(1,  LXOR1);
    unsigned thr = rdlane(arr, K1 - 1);

    // ordered walk: blocks by ascending lower bound; break = prune rest (exact:
    // truncation is monotone, bkey <= real keys, thr only decreases).
    int k = 0;
    unsigned bcur = rdlane(bk, 0);
    bool have = (bcur < thr);
    float4 cur;
    if (have) cur = wxyzw[base + (int)(bcur & 0xFFFu) * 64 + lane];
    while (have) {
        unsigned bnext = rdlane(bk, k + 1);
        bool pf = (bnext < thr);               // prefetch decision (conservative)
        float4 nxt;
        if (pf) nxt = wxyzw[base + (int)(bnext & 0xFFFu) * 64 + lane];
        int jbase = (int)(bcur & 0xFFFu) * 64;
        float dx = cur.x - qx, dy = cur.y - qy, dz = cur.z - qz;
        float d2 = dx * dx + dy * dy + dz * dz;
        unsigned key = (__float_as_uint(d2) & 0xFFFFF000u) | (unsigned)(jbase + lane);
        EVENTS(key);                           // tightens thr
        ++k;
        bcur = bnext;
        have = (bcur < thr);                   // thr only decreased: pf false => have false
        cur = nxt;
    }

    // Epilogue: lanes 1..16 hold the 16 nearest neighbors (lane 0 = self).
    const float* ppb = ppred + (size_t)b * NPTS * 3;
    const int iorig = widx[base + p];
    float s = 0.f;
    if (lane >= 1 && lane <= KNN) {
        int js = (int)(arr & 0xFFFu);
        float4 rc = wxyzw[base + js];
        float rx = rc.x - qx, ry = rc.y - qy, rz = rc.z - qz;
        float dref = sqrtf(rx * rx + ry * ry + rz * rz);
        int nj = widx[base + js];
        float px = ppb[3 * iorig + 0], py = ppb[3 * iorig + 1], pz = ppb[3 * iorig + 2];
        float ax = ppb[3 * nj + 0] - px;
        float ay = ppb[3 * nj + 1] - py;
        float az = ppb[3 * nj + 2] - pz;
        float dpred = sqrtf(ax * ax + ay * ay + az * az);
        s = fmaxf(dpred / (dref + EPSF) - 1.0f, 0.0f);
    }
    // DPP prefix-add within rows of 16; lanes 0..16 hold all nonzeros.
    s += DPPF_SHR(s, 0x111);
    s += DPPF_SHR(s, 0x112);
    s += DPPF_SHR(s, 0x114);
    s += DPPF_SHR(s, 0x118);
    float t15 = __uint_as_float(rdlane(__float_as_uint(s), 15));
    float t16 = __uint_as_float(rdlane(__float_as_uint(s), 16));
    if (lane == 0) partials[q] = t15 + t16;
}

// ---- Kernel 3: deterministic single-block final reduction.
__global__ __launch_bounds__(1024) void reduce_kernel(
    const float* __restrict__ partials, int n, float* __restrict__ out, float scale)
{
    __shared__ float wsum[16];
    float s = 0.f;
    for (int idx = threadIdx.x; idx < n; idx += 1024) s += partials[idx];
    for (int off = 32; off > 0; off >>= 1) s += __shfl_down(s, off);
    if ((threadIdx.x & 63) == 0) wsum[threadIdx.x >> 6] = s;
    __syncthreads();
    if (threadIdx.x == 0) {
        float t = 0.f;
#pragma unroll
        for (int k = 0; k < 16; ++k) t += wsum[k];
        out[0] = t * scale;
    }
}

extern "C" void kernel_launch(void* const* d_in, const int* in_sizes, int n_in,
                              void* d_out, int out_size, void* d_ws, size_t ws_size,
                              hipStream_t stream) {
    const float* pref  = (const float*)d_in[0];
    const float* ppred = (const float*)d_in[1];
    float* out = (float*)d_out;

    const int B  = in_sizes[0] / (NPTS * 3);
    const int NQ = B * NPTS;
    const float scale = 1.0f / ((float)NQ * (float)KNN);

    char* ws = (char*)d_ws;
    float4* wxyzw = (float4*)ws;                                   // B*N*16
    int*    widx  = (int*)   (ws + (size_t)B * NPTS * 16);         // B*N*4
    float4* wbb   = (float4*)(ws + (size_t)B * NPTS * 20);         // B*64*2*16
    float*  partials = (float*)(ws + (size_t)B * NPTS * 20 + (size_t)B * NBLK * 32);

    sort_kernel<<<dim3(B), dim3(1024), 0, stream>>>(pref, wxyzw, widx, wbb);
    knn_main_kernel<<<dim3(NQ / 4), dim3(256), 0, stream>>>(ppred, wxyzw, widx, wbb, partials, NQ);
    reduce_kernel<<<dim3(1), dim3(1024), 0, stream>>>(partials, NQ, out, scale);
}

// Round 19
// 65.569 us; speedup vs baseline: 2.0793x; 1.1542x over previous
//
#include <hip/hip_runtime.h>

#define NPTS  4096
#define KNN   16
#define K1    17            // KNN + self
#define NBLK  64            // candidate blocks per batch == wave width
#define CELLS 4096          // 16^3 Morton cells
#define EPSF  1e-10f

__device__ __forceinline__ unsigned umin_(unsigned a, unsigned b) { return a < b ? a : b; }
__device__ __forceinline__ unsigned umax_(unsigned a, unsigned b) { return a < b ? b : a; }
__device__ __forceinline__ unsigned rdlane(unsigned v, int l) {
    return (unsigned)__builtin_amdgcn_readlane((int)v, l);
}

// cheap cross-lane primitives (DPP = VALU, ds_swizzle = DS pipe, shfl = ds_permute)
#define DPP_XOR1(v)  ((unsigned)__builtin_amdgcn_update_dpp(0, (int)(v), 0xB1, 0xF, 0xF, true))
#define DPP_XOR2(v)  ((unsigned)__builtin_amdgcn_update_dpp(0, (int)(v), 0x4E, 0xF, 0xF, true))
#define SWZ_XOR(v,J) ((unsigned)__builtin_amdgcn_ds_swizzle((int)(v), ((J) << 10) | 0x1F))
#define DPP_SHR1(v)  ((unsigned)__builtin_amdgcn_update_dpp(0, (int)(v), 0x111, 0xF, 0xF, true))
#define DPPF_SHR(vf, CTRL) __uint_as_float((unsigned)__builtin_amdgcn_update_dpp(0, (int)__float_as_uint(vf), CTRL, 0xF, 0xF, true))
#define LXOR1(v)  DPP_XOR1(v)
#define LXOR2(v)  DPP_XOR2(v)
#define LXOR4(v)  SWZ_XOR(v, 4)
#define LXOR8(v)  SWZ_XOR(v, 8)
#define LXOR16(v) SWZ_XOR(v, 16)
#define LXOR32(v) ((unsigned)__shfl_xor((int)(v), 32))

// one compare-exchange stage applied to BOTH sort chains (ILP)
#define BSTEP(K, XORF) do {                                                   \
    unsigned o1_ = XORF(arr), o2_ = XORF(bk);                                 \
    bool tm_ = (((lane & (J_)) == 0) == ((lane & (K)) == 0));                 \
    unsigned mn1_ = umin_(arr, o1_), mx1_ = umax_(arr, o1_);                  \
    unsigned mn2_ = umin_(bk, o2_),  mx2_ = umax_(bk, o2_);                   \
    arr = tm_ ? mn1_ : mx1_; bk = tm_ ? mn2_ : mx2_;                          \
} while (0)

// spread 4 bits to positions 0,3,6,9
__device__ __forceinline__ unsigned sp4(int v) {
    unsigned x = (unsigned)v;
    return (x & 1u) | ((x & 2u) << 2) | ((x & 4u) << 4) | ((x & 8u) << 6);
}

// ---- Kernel 1: per-batch counting sort by 12-bit Morton cell (no bbox here;
// that phase was ~7us serialized on 8 CUs and moved to its own kernel).
// Sort is permutation-only; exactness never depends on it.
__global__ __launch_bounds__(1024) void sort_kernel(
    const float* __restrict__ pref,
    float4* __restrict__ wxyzw, int* __restrict__ widx)
{
    __shared__ unsigned hist[CELLS];          // 16 KB
    __shared__ unsigned short cells[NPTS];    // 8 KB
    __shared__ unsigned wofs[16];
    const int tid  = threadIdx.x;
    const int lane = tid & 63, w = tid >> 6;
    const int b = blockIdx.x;
    const float* prb = pref + (size_t)b * NPTS * 3;
    const size_t base = (size_t)b * NPTS;

    for (int t = tid; t < CELLS; t += 1024) hist[t] = 0u;
    __syncthreads();

    for (int p = tid; p < NPTS; p += 1024) {
        float x = prb[3 * p + 0], y = prb[3 * p + 1], z = prb[3 * p + 2];
        int cx = min(15, max(0, (int)((x + 4.0f) * 2.0f)));
        int cy = min(15, max(0, (int)((y + 4.0f) * 2.0f)));
        int cz = min(15, max(0, (int)((z + 4.0f) * 2.0f)));
        unsigned m = sp4(cx) | (sp4(cy) << 1) | (sp4(cz) << 2);
        cells[p] = (unsigned short)m;
        atomicAdd(&hist[m], 1u);
    }
    __syncthreads();

    // Exclusive scan of hist[4096]; thread t owns cells 4t..4t+3.
    unsigned l0 = hist[4 * tid + 0], l1 = hist[4 * tid + 1];
    unsigned l2 = hist[4 * tid + 2], l3 = hist[4 * tid + 3];
    unsigned s = l0 + l1 + l2 + l3;
    unsigned run = s;
#pragma unroll
    for (int d = 1; d < 64; d <<= 1) {
        unsigned o = __shfl_up(run, d);
        if (lane >= d) run += o;
    }
    if (lane == 63) wofs[w] = run;
    __syncthreads();
    if (tid == 0) {
        unsigned acc = 0;
#pragma unroll
        for (int k = 0; k < 16; ++k) { unsigned t2 = wofs[k]; wofs[k] = acc; acc += t2; }
    }
    __syncthreads();
    unsigned excl = wofs[w] + run - s;
    hist[4 * tid + 0] = excl;
    hist[4 * tid + 1] = excl + l0;
    hist[4 * tid + 2] = excl + l0 + l1;
    hist[4 * tid + 3] = excl + l0 + l1 + l2;
    __syncthreads();

    for (int p = tid; p < NPTS; p += 1024) {
        unsigned c = cells[p];
        unsigned pos = atomicAdd(&hist[c], 1u);
        wxyzw[base + pos] = make_float4(prb[3 * p + 0], prb[3 * p + 1], prb[3 * p + 2], 0.f);
        widx[base + pos]  = p;
    }
}

// ---- Kernel 1b: per-64-block bboxes, parallel across the chip (one bbox per
// wave; 512 waves total vs serialized on 8 CUs before). True min/max of
// actual points -> pruning exactness preserved.
__global__ __launch_bounds__(512) void bbox_kernel(
    const float4* __restrict__ wxyzw, float4* __restrict__ wbb)
{
    const int lane = threadIdx.x & 63;
    const int gb = blockIdx.x * 8 + (threadIdx.x >> 6);   // global bbox id
    const int b  = gb >> 6;                                // NBLK per batch
    const int blk = gb & (NBLK - 1);
    const size_t base = (size_t)b * NPTS;

    float4 c = wxyzw[base + blk * 64 + lane];
    float mnx = c.x, mxx = c.x, mny = c.y, mxy2 = c.y, mnz = c.z, mxz = c.z;
#pragma unroll
    for (int d = 32; d > 0; d >>= 1) {
        mnx  = fminf(mnx,  __shfl_xor(mnx,  d));
        mxx  = fmaxf(mxx,  __shfl_xor(mxx,  d));
        mny  = fminf(mny,  __shfl_xor(mny,  d));
        mxy2 = fmaxf(mxy2, __shfl_xor(mxy2, d));
        mnz  = fminf(mnz,  __shfl_xor(mnz,  d));
        mxz  = fmaxf(mxz,  __shfl_xor(mxz,  d));
    }
    if (lane == 0) {
        wbb[(size_t)gb * 2 + 0] = make_float4(mnx, mny, mnz, 0.f);
        wbb[(size_t)gb * 2 + 1] = make_float4(mxx, mxy2, mxz, 0.f);
    }
}

// DPP-based insertion of broadcast key kk_ into lane-sliced sorted arr
#define EVENTS(KEY) do {                                                      \
    unsigned long long m_ = __ballot((KEY) < thr);                            \
    if (m_) {                                                                 \
        do {                                                                  \
            int l_ = __ffsll(m_) - 1;                                         \
            m_ &= m_ - 1;                                                     \
            unsigned kk_ = rdlane(KEY, l_);                                   \
            unsigned long long lt_ = __ballot(arr < kk_) & 0x1FFFFull;        \
            int pos_ = __popcll(lt_);                                         \
            unsigned up_ = DPP_SHR1(arr);                                     \
            unsigned a15_ = rdlane(arr, 15);                                  \
            up_ = (lane == 16) ? a15_ : up_;                                  \
            arr = (lane == pos_) ? kk_ : ((lane > pos_) ? up_ : arr);         \
        } while (m_);                                                         \
        thr = rdlane(arr, K1 - 1);                                            \
    } } while (0)

// ---- Kernel 2: R10 main verbatim (one query per wave, hash-permuted;
// distance-ordered bbox walk with early exit; exact top-17) EXCEPT the
// epilogue writes ONE partial per block (8192 contiguous floats) instead of
// 32768 hash-scattered per-query floats -> reduce drops from ~8us to ~1us.
__global__ __launch_bounds__(256, 8) void knn_main_kernel(
    const float* __restrict__ ppred,
    const float4* __restrict__ wxyzw, const int* __restrict__ widx,
    const float4* __restrict__ wbb, float* __restrict__ partials, int NQ)
{
    __shared__ float wsum[4];
    const int lane = threadIdx.x & 63;
    const int w    = threadIdx.x >> 6;
    const int wv   = blockIdx.x * 4 + w;
    // odd multiplier mod pow2 is a bijection; mixes spatial regions across waves
    const int q = ((NQ & (NQ - 1)) == 0) ? (int)(((unsigned)wv * 26765u) & (unsigned)(NQ - 1)) : wv;

    const int b = q >> 12;
    const int p = q & (NPTS - 1);              // sorted position = query
    const size_t base = (size_t)b * NPTS;
    const int p0 = p & ~63, ownblk = p >> 6;

    const float4 qc = wxyzw[base + p];         // uniform -> broadcast
    const float qx = qc.x, qy = qc.y, qz = qc.z;

    // own-block candidate keys (self d2 == +0.0 -> key = p = minimum)
    unsigned arr;
    {
        float4 c = wxyzw[base + p0 + lane];
        float dx = c.x - qx, dy = c.y - qy, dz = c.z - qz;
        float d2 = dx * dx + dy * dy + dz * dz;
        arr = (__float_as_uint(d2) & 0xFFFFF000u) | (unsigned)(p0 + lane);
    }
    // bbox lower-bound keys: same truncation as real keys; blk in the index
    // field (blk <= any j in block) => bkey <= every real key in the block.
    unsigned bk;
    {
        float4 mn4 = wbb[((size_t)b * NBLK + lane) * 2 + 0];
        float4 mx4 = wbb[((size_t)b * NBLK + lane) * 2 + 1];
        float ddx = fmaxf(fmaxf(mn4.x - qx, qx - mx4.x), 0.0f);
        float ddy = fmaxf(fmaxf(mn4.y - qy, qy - mx4.y), 0.0f);
        float ddz = fmaxf(fmaxf(mn4.z - qz, qz - mx4.z), 0.0f);
        float bd2 = ddx * ddx + ddy * ddy + ddz * ddz;
        bk = (__float_as_uint(bd2) & 0xFFFFF000u) | (unsigned)lane;
        bk = (lane == ownblk) ? 0xFFFFFFFFu : bk;   // sentinel: never walked
    }

    // joint bitonic sort of arr and bk (ascending), ILP'd through one network
    {
        int J_;
        J_ = 1;  BSTEP(2,  LXOR1);
        J_ = 2;  BSTEP(4,  LXOR2);  J_ = 1; BSTEP(4,  LXOR1);
        J_ = 4;  BSTEP(8,  LXOR4);  J_ = 2; BSTEP(8,  LXOR2);  J_ = 1; BSTEP(8,  LXOR1);
        J_ = 8;  BSTEP(16, LXOR8);  J_ = 4; BSTEP(16, LXOR4);  J_ = 2; BSTEP(16, LXOR2);  J_ = 1; BSTEP(16, LXOR1);
        J_ = 16; BSTEP(32, LXOR16); J_ = 8; BSTEP(32, LXOR8);  J_ = 4; BSTEP(32, LXOR4);  J_ = 2; BSTEP(32, LXOR2); J_ = 1; BSTEP(32, LXOR1);
        J_ = 32; BSTEP(64, LXOR32); J_ = 16; BSTEP(64, LXOR16); J_ = 8; BSTEP(64, LXOR8); J_ = 4; BSTEP(64, LXOR4); J_ = 2; BSTEP(64, LXOR2); J_ = 1; BSTEP(64, LXOR1);
    }
    unsigned thr = rdlane(arr, K1 - 1);

    // ordered walk: blocks by ascending lower bound; break = prune rest (exact:
    // truncation is monotone, bkey <= real keys, thr only decreases).
    int k = 0;
    unsigned bcur = rdlane(bk, 0);
    bool have = (bcur < thr);
    float4 cur;
    if (have) cur = wxyzw[base + (int)(bcur & 0xFFFu) * 64 + lane];
    while (have) {
        unsigned bnext = rdlane(bk, k + 1);
        bool pf = (bnext < thr);               // prefetch decision (conservative)
        float4 nxt;
        if (pf) nxt = wxyzw[base + (int)(bnext & 0xFFFu) * 64 + lane];
        int jbase = (int)(bcur & 0xFFFu) * 64;
        float dx = cur.x - qx, dy = cur.y - qy, dz = cur.z - qz;
        float d2 = dx * dx + dy * dy + dz * dz;
        unsigned key = (__float_as_uint(d2) & 0xFFFFF000u) | (unsigned)(jbase + lane);
        EVENTS(key);                           // tightens thr
        ++k;
        bcur = bnext;
        have = (bcur < thr);                   // thr only decreased: pf false => have false
        cur = nxt;
    }

    // Epilogue: lanes 1..16 hold the 16 nearest neighbors (lane 0 = self).
    const float* ppb = ppred + (size_t)b * NPTS * 3;
    const int iorig = widx[base + p];
    float s = 0.f;
    if (lane >= 1 && lane <= KNN) {
        int js = (int)(arr & 0xFFFu);
        float4 rc = wxyzw[base + js];
        float rx = rc.x - qx, ry = rc.y - qy, rz = rc.z - qz;
        float dref = sqrtf(rx * rx + ry * ry + rz * rz);
        int nj = widx[base + js];
        float px = ppb[3 * iorig + 0], py = ppb[3 * iorig + 1], pz = ppb[3 * iorig + 2];
        float ax = ppb[3 * nj + 0] - px;
        float ay = ppb[3 * nj + 1] - py;
        float az = ppb[3 * nj + 2] - pz;
        float dpred = sqrtf(ax * ax + ay * ay + az * az);
        s = fmaxf(dpred / (dref + EPSF) - 1.0f, 0.0f);
    }
    // DPP prefix-add within rows of 16; lanes 0..16 hold all nonzeros.
    s += DPPF_SHR(s, 0x111);
    s += DPPF_SHR(s, 0x112);
    s += DPPF_SHR(s, 0x114);
    s += DPPF_SHR(s, 0x118);
    float t15 = __uint_as_float(rdlane(__float_as_uint(s), 15));
    float t16 = __uint_as_float(rdlane(__float_as_uint(s), 16));

    // one partial per block (contiguous) -> cheap reduce
    if (lane == 0) wsum[w] = t15 + t16;
    __syncthreads();
    if (threadIdx.x == 0)
        partials[blockIdx.x] = (wsum[0] + wsum[1]) + (wsum[2] + wsum[3]);
}

// ---- Kernel 3: deterministic single-block final reduction (float4 loads).
__global__ __launch_bounds__(1024) void reduce_kernel(
    const float* __restrict__ partials, int n, float* __restrict__ out, float scale)
{
    __shared__ float wsum[16];
    const float4* p4 = (const float4*)partials;
    const int n4 = n >> 2;
    float s = 0.f;
    for (int idx = threadIdx.x; idx < n4; idx += 1024) {
        float4 v = p4[idx];
        s += (v.x + v.y) + (v.z + v.w);
    }
    for (int off = 32; off > 0; off >>= 1) s += __shfl_down(s, off);
    if ((threadIdx.x & 63) == 0) wsum[threadIdx.x >> 6] = s;
    __syncthreads();
    if (threadIdx.x == 0) {
        float t = 0.f;
#pragma unroll
        for (int k = 0; k < 16; ++k) t += wsum[k];
        out[0] = t * scale;
    }
}

extern "C" void kernel_launch(void* const* d_in, const int* in_sizes, int n_in,
                              void* d_out, int out_size, void* d_ws, size_t ws_size,
                              hipStream_t stream) {
    const float* pref  = (const float*)d_in[0];
    const float* ppred = (const float*)d_in[1];
    float* out = (float*)d_out;

    const int B  = in_sizes[0] / (NPTS * 3);
    const int NQ = B * NPTS;
    const int nblocks = NQ / 4;            // 4 waves/block, 1 query/wave
    const float scale = 1.0f / ((float)NQ * (float)KNN);

    char* ws = (char*)d_ws;
    float4* wxyzw = (float4*)ws;                                   // B*N*16
    int*    widx  = (int*)   (ws + (size_t)B * NPTS * 16);         // B*N*4
    float4* wbb   = (float4*)(ws + (size_t)B * NPTS * 20);         // B*64*2*16
    float*  partials = (float*)(ws + (size_t)B * NPTS * 20 + (size_t)B * NBLK * 32);

    sort_kernel<<<dim3(B), dim3(1024), 0, stream>>>(pref, wxyzw, widx);
    bbox_kernel<<<dim3(B * NBLK / 8), dim3(512), 0, stream>>>(wxyzw, wbb);
    knn_main_kernel<<<dim3(nblocks), dim3(256), 0, stream>>>(ppred, wxyzw, widx, wbb, partials, NQ);
    reduce_kernel<<<dim3(1), dim3(1024), 0, stream>>>(partials, nblocks, out, scale);
}